// Round 7
// baseline (706.852 us; speedup 1.0000x reference)
//
#include <hip/hip_runtime.h>

#define HID 2048
#define TSEQ 2048
#define BBATCH 4
#define MROWS 8192   // B*T
#define NHEADS 32

typedef float fvec4 __attribute__((ext_vector_type(4)));
typedef unsigned short usvec4 __attribute__((ext_vector_type(4)));
typedef unsigned short usvec8 __attribute__((ext_vector_type(8)));
typedef __bf16 bh8 __attribute__((ext_vector_type(8)));
typedef float f32x4 __attribute__((ext_vector_type(4)));

__device__ __forceinline__ float bf2f(unsigned short u){
  return __uint_as_float(((unsigned int)u) << 16);
}
__device__ __forceinline__ unsigned short f2bf(float f){
  unsigned int u = __float_as_uint(f);
  return (unsigned short)((u + 0x7fffu + ((u >> 16) & 1u)) >> 16);
}
__device__ __forceinline__ void gll16(const void* g, void* lds){
  __builtin_amdgcn_global_load_lds(
      (const __attribute__((address_space(1))) unsigned int*)g,
      (__attribute__((address_space(3))) unsigned int*)lds, 16, 0, 0);
}

// ---------------- transpose + cast f32 -> bf16 : out[c][r] = in[r][c] -------
__global__ void tcast_kernel(const float* __restrict__ in, unsigned short* __restrict__ out,
                             int R, int C){
  __shared__ float tile[32][33];
  int c0 = blockIdx.x * 32, r0 = blockIdx.y * 32;
  int tx = threadIdx.x, ty = threadIdx.y;
  for (int i = ty; i < 32; i += 8){
    int r = r0 + i, c = c0 + tx;
    tile[i][tx] = (r < R && c < C) ? in[(size_t)r * C + c] : 0.f;
  }
  __syncthreads();
  for (int i = ty; i < 32; i += 8){
    int c = c0 + i, r = r0 + tx;
    if (c < C && r < R) out[(size_t)c * R + r] = f2bf(tile[tx][i]);
  }
}

__global__ void zero_stats_kernel(float* __restrict__ gsum, float* __restrict__ gsqs){
  int i = threadIdx.x;  // 128 threads
  gsum[i] = 0.f;
  gsqs[i] = 0.f;
}

// ---------------- token-shift time_mix -> bf16 ------------------------------
__global__ void tmix_kernel(const float* __restrict__ hidden, const float* __restrict__ attn_x,
                            const float* __restrict__ tmx, unsigned short* __restrict__ tm){
  int i4 = blockIdx.x * 256 + threadIdx.x;        // over MROWS*HID/4
  int row = i4 >> 9;
  int c4 = i4 & 511;
  fvec4 x = *(const fvec4*)&hidden[(size_t)i4 * 4];
  fvec4 p;
  if ((row & (TSEQ - 1)) == 0){
    int b = row >> 11;
    p = *(const fvec4*)&attn_x[b * HID + c4 * 4];
  } else {
    p = *(const fvec4*)&hidden[(size_t)(i4 - 512) * 4];
  }
  fvec4 tx = *(const fvec4*)&tmx[c4 * 4];
  fvec4 t = x + (p - x) * tx;
  usvec4 o;
  o[0]=f2bf(t[0]); o[1]=f2bf(t[1]); o[2]=f2bf(t[2]); o[3]=f2bf(t[3]);
  *(usvec4*)&tm[(size_t)i4 * 4] = o;
}

// ---------------- m97-style bf16 GEMM (kept for the N=160 w1 GEMM) ----------
// ACT: 0 none, 1 tanh, 2 silu.  OUTBF16: store bf16 else f32.
template<int ACT, int OUTBF16>
__global__ __launch_bounds__(256, 2) void gemm_kernel(
    const unsigned short* __restrict__ A, const unsigned short* __restrict__ Bt,
    void* __restrict__ Cptr, int M, int N, int K, int ldc)
{
  __shared__ unsigned short As[128 * 32];
  __shared__ unsigned short Bs[128 * 32];
  const int tid = threadIdx.x;
  const int lane = tid & 63;
  const int w = tid >> 6;
  const int wr = w >> 1, wc = w & 1;
  const int lr = lane & 15, lq = lane >> 4;
  const int rowBase = blockIdx.y * 128;
  const int colBase = blockIdx.x * 128;

  const int arow = tid >> 2;
  const int ach = tid & 3;
  const unsigned short* aptr0 = A + (size_t)(rowBase + arow) * K + ach * 8;
  const unsigned short* aptr1 = aptr0 + (size_t)64 * K;
  int br0 = colBase + arow;      if (br0 > N - 1) br0 = N - 1;
  int br1 = colBase + arow + 64; if (br1 > N - 1) br1 = N - 1;
  const unsigned short* bptr0 = Bt + (size_t)br0 * K + ach * 8;
  const unsigned short* bptr1 = Bt + (size_t)br1 * K + ach * 8;

  f32x4 acc[4][4] = {};

  const int nk = K >> 5;
  for (int kk = 0; kk < nk; ++kk){
    gll16(aptr0, &As[tid * 8]);
    gll16(aptr1, &As[(tid + 256) * 8]);
    gll16(bptr0, &Bs[tid * 8]);
    gll16(bptr1, &Bs[(tid + 256) * 8]);
    aptr0 += 32; aptr1 += 32; bptr0 += 32; bptr1 += 32;
    __syncthreads();
    bh8 af[4], bfv[4];
    #pragma unroll
    for (int m = 0; m < 4; ++m)
      af[m] = *reinterpret_cast<const bh8*>(&As[(wr * 64 + m * 16 + lr) * 32 + lq * 8]);
    #pragma unroll
    for (int n = 0; n < 4; ++n)
      bfv[n] = *reinterpret_cast<const bh8*>(&Bs[(wc * 64 + n * 16 + lr) * 32 + lq * 8]);
    #pragma unroll
    for (int m = 0; m < 4; ++m)
      #pragma unroll
      for (int n = 0; n < 4; ++n)
        acc[m][n] = __builtin_amdgcn_mfma_f32_16x16x32_bf16(af[m], bfv[n], acc[m][n], 0, 0, 0);
    __syncthreads();
  }

  #pragma unroll
  for (int m = 0; m < 4; ++m){
    int gr0 = rowBase + wr * 64 + m * 16 + lq * 4;
    #pragma unroll
    for (int n = 0; n < 4; ++n){
      int gc = colBase + wc * 64 + n * 16 + lr;
      if (gc < N){
        #pragma unroll
        for (int q = 0; q < 4; ++q){
          float v = acc[m][n][q];
          if constexpr (ACT == 1) v = tanhf(v);
          else if constexpr (ACT == 2) v = v / (1.0f + __expf(-v));
          size_t off = (size_t)(gr0 + q) * ldc + gc;
          if constexpr (OUTBF16) ((unsigned short*)Cptr)[off] = f2bf(v);
          else                   ((float*)Cptr)[off] = v;
        }
      }
    }
  }
}

// -------- 256x256 bf16 GEMM, BK=64, 8 waves, dbuf LDS + prefetch overlap ----
// C = A(MxK) * Bt(NxK)^T.  M,N multiples of 256, K multiple of 64, ldc=N.
// LDS XOR-swizzle (chunk ^= row&7) applied on BOTH stage-source and ds_read.
// K-loop reads the MINIMAL fragment set: per k-half, af[8]+bf[4] loaded once
// (24 ds_read_b128/tile vs 48 before) then 32 MFMA — LDS no longer the pipe.
template<int ACT, int OUTBF16>
__global__ __launch_bounds__(512, 2) void gemm256_kernel(
    const unsigned short* __restrict__ A, const unsigned short* __restrict__ Bt,
    void* __restrict__ Cptr, int K)
{
  __shared__ unsigned short smem[65536];   // 128 KiB: 2 x (A 16384 + B 16384)
  const int tid = threadIdx.x;
  const int lane = tid & 63, w = tid >> 6;
  const int wr = w >> 2, wc = w & 3;           // 2M x 4N waves
  const int lr = lane & 15, lq = lane >> 4;
  const int rowBase = blockIdx.y * 256;
  const int colBase = blockIdx.x * 256;
  const int N = gridDim.x * 256;               // = ldc

  // staging: 8 x 16B chunks per thread per K-tile (4 A-rounds + 4 B-rounds)
  const unsigned short* srcp[8];
  int dstoff[8];
  #pragma unroll
  for (int l = 0; l < 8; ++l){
    int ci = (l & 3) * 512 + tid;     // chunk index 0..2047 within matrix tile
    int r = ci >> 3, c = ci & 7;      // LDS row 0..255, LDS chunk 0..7
    int gchunk = c ^ (r & 7);         // pre-swizzled global chunk
    const unsigned short* base = (l < 4) ? A : Bt;
    int grow = ((l < 4) ? rowBase : colBase) + r;
    srcp[l] = base + (size_t)grow * K + gchunk * 8;
    dstoff[l] = ((l < 4) ? 0 : 16384) + ci * 8;
  }

  f32x4 acc[8][4] = {};

  auto STAGE = [&](unsigned short* buf){
    #pragma unroll
    for (int l = 0; l < 8; ++l){
      gll16(srcp[l], buf + dstoff[l]);
      srcp[l] += 64;                  // next K-tile (64 elements)
    }
  };

  auto COMPUTE = [&](const unsigned short* buf){
    const unsigned short* aB = buf;
    const unsigned short* bB = buf + 16384;
    #pragma unroll
    for (int s = 0; s < 2; ++s){
      bh8 af[8], bf[4];
      #pragma unroll
      for (int m = 0; m < 8; ++m){
        int row = wr * 128 + m * 16 + lr;
        af[m] = *reinterpret_cast<const bh8*>(
            &aB[row * 64 + (((s * 4 + lq) ^ (row & 7)) * 8)]);
      }
      #pragma unroll
      for (int n = 0; n < 4; ++n){
        int row = wc * 64 + n * 16 + lr;
        bf[n] = *reinterpret_cast<const bh8*>(
            &bB[row * 64 + (((s * 4 + lq) ^ (row & 7)) * 8)]);
      }
      #pragma unroll
      for (int m = 0; m < 8; ++m)
        #pragma unroll
        for (int n = 0; n < 4; ++n)
          acc[m][n] = __builtin_amdgcn_mfma_f32_16x16x32_bf16(af[m], bf[n], acc[m][n], 0, 0, 0);
    }
  };

  unsigned short* buf0 = smem;
  unsigned short* buf1 = smem + 32768;

  STAGE(buf0);
  __syncthreads();
  const int nt = K >> 6;
  for (int t = 0; t < nt - 1; ++t){
    unsigned short* cur = (t & 1) ? buf1 : buf0;
    unsigned short* nxt = (t & 1) ? buf0 : buf1;
    STAGE(nxt);         // issued EARLY: in flight across the whole compute
    COMPUTE(cur);
    __syncthreads();    // drains vmcnt (loads issued ~64 MFMA ago) + barrier
  }
  COMPUTE((nt & 1) ? buf0 : buf1);

  #pragma unroll
  for (int m = 0; m < 8; ++m){
    int gr0 = rowBase + wr * 128 + m * 16 + lq * 4;
    #pragma unroll
    for (int n = 0; n < 4; ++n){
      int gc = colBase + wc * 64 + n * 16 + lr;
      #pragma unroll
      for (int q = 0; q < 4; ++q){
        float v = acc[m][n][q];
        if constexpr (ACT == 1) v = tanhf(v);
        else if constexpr (ACT == 2) v = v / (1.0f + __expf(-v));
        size_t off = (size_t)(gr0 + q) * N + gc;
        if constexpr (OUTBF16) ((unsigned short*)Cptr)[off] = f2bf(v);
        else                   ((float*)Cptr)[off] = v;
      }
    }
  }
}

// ------- einsum(4x K=32) via MFMA + lerp construction of xk/xv/xr/xg --------
__global__ __launch_bounds__(256) void mix_kernel(
    const float* __restrict__ xxx, const float* __restrict__ hidden,
    const float* __restrict__ attn_x, const float* __restrict__ w2,
    const float* __restrict__ tmk, const float* __restrict__ tmv,
    const float* __restrict__ tmr, const float* __restrict__ tmg,
    unsigned short* __restrict__ xk, unsigned short* __restrict__ xv,
    unsigned short* __restrict__ xr, unsigned short* __restrict__ xg)
{
  __shared__ __attribute__((aligned(16))) unsigned short smem[20992];
  unsigned short* xs   = smem;           // [64][168] bf16
  unsigned short* w2t  = smem + 10752;   // [4][64][40] bf16 (w2t[n][cc][j])
  unsigned short* out4 = smem;           // [4][64][72] bf16 (phase B overlay)

  const int tid = threadIdx.x;
  const int r0 = blockIdx.y * 64, c0 = blockIdx.x * 64;
  const int w = tid >> 6, lane = tid & 63, lr = lane & 15, lq = lane >> 4;

  for (int idx = tid; idx < 64 * 40; idx += 256){
    int r = idx / 40, cq = idx - r * 40;
    fvec4 v = *(const fvec4*)&xxx[(size_t)(r0 + r) * 160 + cq * 4];
    usvec4 o;
    o[0]=f2bf(v[0]); o[1]=f2bf(v[1]); o[2]=f2bf(v[2]); o[3]=f2bf(v[3]);
    *(usvec4*)&xs[r * 168 + cq * 4] = o;
  }
  for (int idx = tid; idx < 4 * 32 * 16; idx += 256){
    int n = idx >> 9;
    int rem = idx & 511;
    int j = rem >> 4, cq = rem & 15;
    fvec4 v = *(const fvec4*)&w2[(size_t)((n + 1) * 32 + j) * HID + c0 + cq * 4];
    #pragma unroll
    for (int cc = 0; cc < 4; ++cc)
      w2t[(n * 64 + cq * 4 + cc) * 40 + j] = f2bf(v[cc]);
  }
  __syncthreads();

  f32x4 acc[4][4] = {};
  #pragma unroll
  for (int n = 0; n < 4; ++n){
    bh8 afr = *reinterpret_cast<const bh8*>(&xs[(w * 16 + lr) * 168 + (n + 1) * 32 + lq * 8]);
    #pragma unroll
    for (int ct = 0; ct < 4; ++ct){
      bh8 bfr = *reinterpret_cast<const bh8*>(&w2t[(n * 64 + ct * 16 + lr) * 40 + lq * 8]);
      acc[ct][n] = __builtin_amdgcn_mfma_f32_16x16x32_bf16(afr, bfr, acc[ct][n], 0, 0, 0);
    }
  }
  __syncthreads();

  #pragma unroll
  for (int ct = 0; ct < 4; ++ct){
    int gc = c0 + ct * 16 + lr;
    float tk_ = tmk[gc], tv_ = tmv[gc], tr_ = tmr[gc], tg_ = tmg[gc];
    #pragma unroll
    for (int q = 0; q < 4; ++q){
      int row64 = w * 16 + lq * 4 + q;
      int gr = r0 + row64;
      size_t rowoff = (size_t)gr * HID + gc;
      float xx = hidden[rowoff];
      float pp = ((gr & (TSEQ - 1)) == 0) ? attn_x[(gr >> 11) * HID + gc]
                                          : hidden[rowoff - HID];
      float dxv = pp - xx;
      int lo = row64 * 72 + ct * 16 + lr;
      out4[(0 * 64 * 72) + lo] = f2bf(xx + dxv * (tk_ + acc[ct][0][q]));
      out4[(1 * 64 * 72) + lo] = f2bf(xx + dxv * (tv_ + acc[ct][1][q]));
      out4[(2 * 64 * 72) + lo] = f2bf(xx + dxv * (tr_ + acc[ct][2][q]));
      out4[(3 * 64 * 72) + lo] = f2bf(xx + dxv * (tg_ + acc[ct][3][q]));
    }
  }
  __syncthreads();

  #pragma unroll
  for (int a = 0; a < 4; ++a){
    unsigned short* dst = (a == 0) ? xk : (a == 1) ? xv : (a == 2) ? xr : xg;
    #pragma unroll
    for (int pass = 0; pass < 2; ++pass){
      int row64 = pass * 32 + (tid >> 3);
      int c8 = (tid & 7) * 8;
      usvec8 v8 = *(const usvec8*)&out4[(a * 64 + row64) * 72 + c8];
      *(usvec8*)&dst[(size_t)(r0 + row64) * HID + c0 + c8] = v8;
    }
  }
}

// --------- attention via MFMA: out0 = r@akv + rk*v ; group stats ------------
__global__ __launch_bounds__(256) void attn_kernel(
    const unsigned short* __restrict__ rb, const unsigned short* __restrict__ kb,
    const unsigned short* __restrict__ vb, const float* __restrict__ attn_kv,
    const float* __restrict__ faaaa, unsigned short* __restrict__ out0b,
    float* __restrict__ gsum, float* __restrict__ gsqs)
{
  const int bh = blockIdx.y;           // 128 = b*32+h
  const int b = bh >> 5, h = bh & 31;
  const int tid = threadIdx.x, lane = tid & 63, w = tid >> 6;
  const int lr = lane & 15, lq = lane >> 4;
  const int t0 = blockIdx.x * 256 + w * 64;
  const size_t rowbase = (size_t)(b * TSEQ + t0) * HID + h * 64;

  const float* akvp = attn_kv + (size_t)bh * 4096;
  bh8 bfr[2][4];
  #pragma unroll
  for (int kk = 0; kk < 2; ++kk)
    #pragma unroll
    for (int n = 0; n < 4; ++n)
      #pragma unroll
      for (int j = 0; j < 8; ++j)
        bfr[kk][n][j] = (__bf16)akvp[(kk * 32 + lq * 8 + j) * 64 + n * 16 + lr];

  float fa0[8], fa1[8];
  #pragma unroll
  for (int j = 0; j < 8; ++j){
    fa0[j] = faaaa[h * 64 + lq * 8 + j];
    fa1[j] = faaaa[h * 64 + 32 + lq * 8 + j];
  }

  __shared__ __attribute__((aligned(16))) float rk_s[4][64];
  __shared__ __attribute__((aligned(16))) unsigned short outb[4][64][72];

  f32x4 acc[4][4] = {};
  #pragma unroll
  for (int m = 0; m < 4; ++m){
    size_t ra = rowbase + (size_t)(m * 16 + lr) * HID;
    bh8 a0 = *reinterpret_cast<const bh8*>(&rb[ra + lq * 8]);
    bh8 a1 = *reinterpret_cast<const bh8*>(&rb[ra + 32 + lq * 8]);
    usvec8 k0 = *reinterpret_cast<const usvec8*>(&kb[ra + lq * 8]);
    usvec8 k1 = *reinterpret_cast<const usvec8*>(&kb[ra + 32 + lq * 8]);
    float p = 0.f;
    #pragma unroll
    for (int j = 0; j < 8; ++j){
      p += (float)a0[j] * fa0[j] * bf2f(k0[j]);
      p += (float)a1[j] * fa1[j] * bf2f(k1[j]);
    }
    p += __shfl_xor(p, 16, 64);
    p += __shfl_xor(p, 32, 64);
    if (lq == 0) rk_s[w][m * 16 + lr] = p;
    #pragma unroll
    for (int n = 0; n < 4; ++n){
      acc[m][n] = __builtin_amdgcn_mfma_f32_16x16x32_bf16(a0, bfr[0][n], acc[m][n], 0, 0, 0);
      acc[m][n] = __builtin_amdgcn_mfma_f32_16x16x32_bf16(a1, bfr[1][n], acc[m][n], 0, 0, 0);
    }
  }
  __syncthreads();

  float ssum = 0.f, ssq = 0.f;
  #pragma unroll
  for (int m = 0; m < 4; ++m){
    fvec4 rk4 = *(const fvec4*)&rk_s[w][m * 16 + lq * 4];
    #pragma unroll
    for (int n = 0; n < 4; ++n){
      int col = n * 16 + lr;
      #pragma unroll
      for (int q = 0; q < 4; ++q){
        int row = m * 16 + lq * 4 + q;
        float vv = bf2f(vb[rowbase + (size_t)row * HID + col]);
        float o = acc[m][n][q] + rk4[q] * vv;
        ssum += o; ssq += o * o;
        outb[w][row][col] = f2bf(o);
      }
    }
  }
  __syncthreads();
  #pragma unroll
  for (int pass = 0; pass < 8; ++pass){
    int row = pass * 8 + (lane >> 3);
    int c8 = (lane & 7) * 8;
    usvec8 o8 = *(const usvec8*)&outb[w][row][c8];
    *(usvec8*)&out0b[rowbase + (size_t)row * HID + c8] = o8;
  }
  #pragma unroll
  for (int off2 = 32; off2 > 0; off2 >>= 1){
    ssum += __shfl_xor(ssum, off2, 64);
    ssq  += __shfl_xor(ssq,  off2, 64);
  }
  if (lane == 0){ atomicAdd(&gsum[bh], ssum); atomicAdd(&gsqs[bh], ssq); }
}

__global__ void gn_stats_kernel(const float* __restrict__ gsum, const float* __restrict__ gsqs,
                                float* __restrict__ meaninv){
  int g = threadIdx.x;  // 128 groups
  const float n = (float)(TSEQ * 64);
  float mean = gsum[g] / n;
  float var = gsqs[g] / n - mean * mean;
  meaninv[2 * g]     = mean;
  meaninv[2 * g + 1] = rsqrtf(var + 1e-5f * 64.0f * 64.0f);
}

__global__ void ynorm_kernel(const unsigned short* __restrict__ out0b,
                             const unsigned short* __restrict__ gb,
                             const float* __restrict__ meaninv, const float* __restrict__ gamma,
                             const float* __restrict__ beta, unsigned short* __restrict__ yb){
  int i4 = blockIdx.x * 256 + threadIdx.x;
  int row = i4 >> 9, c4 = i4 & 511;
  int b = row >> 11;
  int c = c4 * 4;
  int g = b * 32 + (c >> 6);
  float mean = meaninv[2 * g], inv = meaninv[2 * g + 1];
  usvec4 o4 = *(const usvec4*)&out0b[(size_t)i4 * 4];
  usvec4 gv = *(const usvec4*)&gb[(size_t)i4 * 4];
  fvec4 ga = *(const fvec4*)&gamma[c];
  fvec4 be = *(const fvec4*)&beta[c];
  usvec4 y;
  #pragma unroll
  for (int cc = 0; cc < 4; ++cc){
    float val = ((bf2f(o4[cc]) - mean) * inv * ga[cc] + be[cc]) * bf2f(gv[cc]);
    y[cc] = f2bf(val);
  }
  *(usvec4*)&yb[(size_t)i4 * 4] = y;
}

// ---------------- exact f32 last-row path (w / k_last / v_last) -------------
__global__ void lastrow_mix_kernel(const float* __restrict__ xxx, const float* __restrict__ hidden,
    const float* __restrict__ w2, const float* __restrict__ tmw, const float* __restrict__ tmk,
    const float* __restrict__ tmv, float* __restrict__ xw_l, float* __restrict__ xk_l,
    float* __restrict__ xv_l){
  int b = blockIdx.y;
  int c = blockIdx.x * 256 + threadIdx.x;
  __shared__ float xsr[160];
  int i = b * TSEQ + (TSEQ - 1);
  if (threadIdx.x < 160) xsr[threadIdx.x] = xxx[(size_t)i * 160 + threadIdx.x];
  __syncthreads();
  float mw = 0.f, mk = 0.f, mv = 0.f;
  for (int j = 0; j < 32; ++j){
    mw += xsr[j]      * w2[(size_t)(j)      * HID + c];
    mk += xsr[32 + j] * w2[(size_t)(32 + j) * HID + c];
    mv += xsr[64 + j] * w2[(size_t)(64 + j) * HID + c];
  }
  float x = hidden[(size_t)i * HID + c];
  float prev = hidden[(size_t)(i - 1) * HID + c];
  float dx = prev - x;
  xw_l[b * HID + c] = x + dx * (tmw[c] + mw);
  xk_l[b * HID + c] = x + dx * (tmk[c] + mk);
  xv_l[b * HID + c] = x + dx * (tmv[c] + mv);
}

// ---- decay: hdec[b][j] = tanh(sum_c xw_l[b][c]*tdw1[c][j]) — split+reduce --
__global__ void decay1_part_kernel(const float* __restrict__ xw_l, const float* __restrict__ tdw1,
                                   float* __restrict__ dpart){
  int b = blockIdx.y;           // 4
  int chunk = blockIdx.x;       // 16 chunks of 128 c-rows
  int j = threadIdx.x & 63, sub = threadIdx.x >> 6;   // 4 subs x 32 rows
  float s = 0.f;
  int cbase = chunk * 128 + sub * 32;
  for (int r = 0; r < 32; ++r){
    int c = cbase + r;
    s += xw_l[b * HID + c] * tdw1[(size_t)c * 64 + j];
  }
  __shared__ float red[4][64];
  red[sub][j] = s;
  __syncthreads();
  if (sub == 0)
    dpart[((size_t)b * 16 + chunk) * 64 + j] = red[0][j] + red[1][j] + red[2][j] + red[3][j];
}

__global__ void decay1_reduce_kernel(const float* __restrict__ dpart, float* __restrict__ hdec){
  int tid = threadIdx.x;        // 256 = 4 b x 64 j
  int b = tid >> 6, j = tid & 63;
  float s = 0.f;
  #pragma unroll
  for (int chunk = 0; chunk < 16; ++chunk)
    s += dpart[((size_t)b * 16 + chunk) * 64 + j];
  hdec[b * 64 + j] = tanhf(s);
}

// ---- last-row k/v GEMVs: k-chunked partials (wide grid) + reduce -----------
__global__ __launch_bounds__(256) void lastrow_kv_part_kernel(
    const float* __restrict__ xk_l, const float* __restrict__ xv_l,
    const float* __restrict__ keyw, const float* __restrict__ valw,
    float* __restrict__ kpart, float* __restrict__ vpart){
  int c = blockIdx.x * 256 + threadIdx.x;   // 8 blocks -> 2048 cols
  int chunk = blockIdx.y;                   // 16 chunks of 128 rows
  __shared__ float xs[2][4][128];
  for (int i = threadIdx.x; i < 512; i += 256){
    int b = i >> 7, r = i & 127;
    xs[0][b][r] = xk_l[b * HID + chunk * 128 + r];
    xs[1][b][r] = xv_l[b * HID + chunk * 128 + r];
  }
  __syncthreads();
  float ka[4] = {0,0,0,0}, va[4] = {0,0,0,0};
  for (int r = 0; r < 128; ++r){
    int c2 = chunk * 128 + r;
    float kw = keyw[(size_t)c2 * HID + c];
    float vw = valw[(size_t)c2 * HID + c];
    #pragma unroll
    for (int b = 0; b < 4; ++b){
      ka[b] += xs[0][b][r] * kw;
      va[b] += xs[1][b][r] * vw;
    }
  }
  #pragma unroll
  for (int b = 0; b < 4; ++b){
    kpart[((size_t)chunk * 4 + b) * HID + c] = ka[b];
    vpart[((size_t)chunk * 4 + b) * HID + c] = va[b];
  }
}

__global__ void lastrow_kv_reduce_kernel(
    const float* __restrict__ kpart, const float* __restrict__ vpart,
    const float* __restrict__ hdec, const float* __restrict__ tdw2,
    const float* __restrict__ tdecay, float* __restrict__ klast,
    float* __restrict__ vlast, float* __restrict__ wlast){
  int c = blockIdx.x * 256 + threadIdx.x;   // 8 blocks -> 2048 cols
  float ka[4] = {0,0,0,0}, va[4] = {0,0,0,0};
  for (int chunk = 0; chunk < 16; ++chunk){
    #pragma unroll
    for (int b = 0; b < 4; ++b){
      ka[b] += kpart[((size_t)chunk * 4 + b) * HID + c];
      va[b] += vpart[((size_t)chunk * 4 + b) * HID + c];
    }
  }
  float tdc = tdecay[c];
  float td[4] = {tdc, tdc, tdc, tdc};
  for (int j = 0; j < 64; ++j){
    float w2v = tdw2[(size_t)j * HID + c];
    #pragma unroll
    for (int b = 0; b < 4; ++b) td[b] += hdec[b * 64 + j] * w2v;
  }
  #pragma unroll
  for (int b = 0; b < 4; ++b){
    klast[b * HID + c] = ka[b];
    vlast[b * HID + c] = va[b];
    wlast[b * HID + c] = expf(-expf(td[b]));
  }
}

__global__ void newkv_kernel(const float* __restrict__ klast, const float* __restrict__ vlast,
    const float* __restrict__ wlast, const float* __restrict__ attn_kv,
    float* __restrict__ outkv){
  int idx = blockIdx.x * 256 + threadIdx.x;  // < 524288
  int b = idx >> 17;
  int h = (idx >> 12) & 31;
  int d = (idx >> 6) & 63;
  int e = idx & 63;
  float kl = klast[b * HID + h * 64 + d];
  float vl = vlast[b * HID + h * 64 + e];
  float wl = wlast[b * HID + h * 64 + d];
  outkv[idx] = kl * vl + wl * attn_kv[idx];
}

__global__ void copies_kernel(const float* __restrict__ hidden, const float* __restrict__ ffnx,
                              float* __restrict__ out_attnx, float* __restrict__ out_ffnx){
  int i = blockIdx.x * 256 + threadIdx.x;
  if (i < BBATCH * HID){
    int b = i >> 11, c = i & 2047;
    out_attnx[i] = hidden[((size_t)(b * TSEQ + TSEQ - 1)) * HID + c];
    out_ffnx[i] = ffnx[i];
  }
}

// ---------------------------------------------------------------------------
extern "C" void kernel_launch(void* const* d_in, const int* in_sizes, int n_in,
                              void* d_out, int out_size, void* d_ws, size_t ws_size,
                              hipStream_t stream)
{
  (void)in_sizes; (void)n_in; (void)out_size;
  const float* hidden = (const float*)d_in[0];
  const float* attn_x = (const float*)d_in[1];
  const float* attn_kv = (const float*)d_in[2];
  const float* ffn_x = (const float*)d_in[3];
  const float* tmaa_x = (const float*)d_in[4];
  const float* tmaa_w = (const float*)d_in[5];
  const float* tmaa_k = (const float*)d_in[6];
  const float* tmaa_v = (const float*)d_in[7];
  const float* tmaa_r = (const float*)d_in[8];
  const float* tmaa_g = (const float*)d_in[9];
  const float* w1 = (const float*)d_in[10];
  const float* w2 = (const float*)d_in[11];
  const float* tdecay = (const float*)d_in[12];
  const float* tdw1 = (const float*)d_in[13];
  const float* tdw2 = (const float*)d_in[14];
  const float* faaaa = (const float*)d_in[15];
  const float* recw = (const float*)d_in[16];
  const float* keyw = (const float*)d_in[17];
  const float* valw = (const float*)d_in[18];
  const float* gatew = (const float*)d_in[19];
  const float* outw = (const float*)d_in[20];
  const float* gamma = (const float*)d_in[21];
  const float* beta = (const float*)d_in[22];

  // output segments (all f32): out | new_attn_x | new_attn_kv | ffn_x
  float* out_main  = (float*)d_out;
  float* out_attnx = out_main + (size_t)16777216;
  float* out_kv    = out_attnx + 8192;
  float* out_ffn   = out_kv + 524288;

  // Early scratch inside d_out (finalized only by the last GEMM):
  //  phase 1 (GEMMs): 4 transposed bf16 weights in [0,32MiB)
  //  phase 2 (attn..ynorm): bf16 out0 in [0,32MiB)
  unsigned short* wr_t = (unsigned short*)d_out;              // 2048x2048 bf16
  unsigned short* wk_t = wr_t + (size_t)4194304;
  unsigned short* wv_t = wk_t + (size_t)4194304;
  unsigned short* wg_t = wv_t + (size_t)4194304;              // ends at 32 MiB
  unsigned short* out0b = (unsigned short*)d_out;             // MROWS*HID bf16

  // workspace layout (~175 MiB), liveness-aliased big buffers:
  //   A: tm -> xg   B: xr -> kb -> yb   C: xk -> vb   D: xv -> gb   E: rb
  char* ws = (char*)d_ws;
  size_t off = 0;
  auto alloc = [&](size_t bytes) -> void* {
    void* p = ws + off; off += (bytes + 255) & ~(size_t)255; return p;
  };
  unsigned short* wo_t = (unsigned short*)alloc(2048ull * 2048 * 2);
  unsigned short* w1_t = (unsigned short*)alloc(160ull * 2048 * 2);
  float* xxx           = (float*)alloc((size_t)MROWS * 160 * 4);
  unsigned short* bufA = (unsigned short*)alloc((size_t)MROWS * HID * 2);
  unsigned short* bufB = (unsigned short*)alloc((size_t)MROWS * HID * 2);
  unsigned short* bufC = (unsigned short*)alloc((size_t)MROWS * HID * 2);
  unsigned short* bufD = (unsigned short*)alloc((size_t)MROWS * HID * 2);
  unsigned short* bufE = (unsigned short*)alloc((size_t)MROWS * HID * 2);
  float* gsum    = (float*)alloc(128 * 4);
  float* gsqs    = (float*)alloc(128 * 4);
  float* meaninv = (float*)alloc(256 * 4);
  float* xw_l  = (float*)alloc(BBATCH * HID * 4);
  float* xk_l  = (float*)alloc(BBATCH * HID * 4);
  float* xv_l  = (float*)alloc(BBATCH * HID * 4);
  float* klast = (float*)alloc(BBATCH * HID * 4);
  float* vlast = (float*)alloc(BBATCH * HID * 4);
  float* wlast = (float*)alloc(BBATCH * HID * 4);
  float* hdec  = (float*)alloc(BBATCH * 64 * 4);
  float* kpart = (float*)alloc(16ull * BBATCH * HID * 4);
  float* vpart = (float*)alloc(16ull * BBATCH * HID * 4);
  float* dpart = (float*)alloc((size_t)BBATCH * 16 * 64 * 4);

  if (off > ws_size) return;   // diagnostic: ws too small -> clean absmax fail

  unsigned short* tm = bufA;   // live: tmix .. w1-GEMM
  unsigned short* xg = bufA;   // live: mix .. g-GEMM
  unsigned short* xr = bufB;   // live: mix .. r-GEMM
  unsigned short* kb = bufB;   // live: k-GEMM .. attn
  unsigned short* yb = bufB;   // live: ynorm .. out-GEMM
  unsigned short* xk = bufC;   // live: mix .. k-GEMM
  unsigned short* vb = bufC;   // live: v-GEMM .. attn
  unsigned short* xv = bufD;   // live: mix .. v-GEMM
  unsigned short* gb = bufD;   // live: g-GEMM .. ynorm
  unsigned short* rb = bufE;   // live: r-GEMM .. attn

  dim3 tb(32, 8);
  tcast_kernel<<<dim3(64, 64), tb, 0, stream>>>(recw,  wr_t, 2048, 2048);
  tcast_kernel<<<dim3(64, 64), tb, 0, stream>>>(keyw,  wk_t, 2048, 2048);
  tcast_kernel<<<dim3(64, 64), tb, 0, stream>>>(valw,  wv_t, 2048, 2048);
  tcast_kernel<<<dim3(64, 64), tb, 0, stream>>>(gatew, wg_t, 2048, 2048);
  tcast_kernel<<<dim3(64, 64), tb, 0, stream>>>(outw,  wo_t, 2048, 2048);
  tcast_kernel<<<dim3(5, 64),  tb, 0, stream>>>(w1,    w1_t, 2048, 160);
  zero_stats_kernel<<<1, 128, 0, stream>>>(gsum, gsqs);

  tmix_kernel<<<16384, 256, 0, stream>>>(hidden, attn_x, tmaa_x, tm);

  gemm_kernel<1, 0><<<dim3(2, 64), 256, 0, stream>>>(tm, w1_t, xxx, MROWS, 160, HID, 160);

  mix_kernel<<<dim3(32, 128), 256, 0, stream>>>(xxx, hidden, attn_x, w2,
      tmaa_k, tmaa_v, tmaa_r, tmaa_g, xk, xv, xr, xg);

  // big GEMMs: 256^2 tile, dbuf prefetch, grid 8x32 = 256 blocks (1/CU)
  gemm256_kernel<0, 1><<<dim3(8, 32), 512, 0, stream>>>(xr, wr_t, rb, HID);
  gemm256_kernel<0, 1><<<dim3(8, 32), 512, 0, stream>>>(xk, wk_t, kb, HID);
  gemm256_kernel<0, 1><<<dim3(8, 32), 512, 0, stream>>>(xv, wv_t, vb, HID);
  gemm256_kernel<2, 1><<<dim3(8, 32), 512, 0, stream>>>(xg, wg_t, gb, HID);

  // attn writes bf16 out0 over d_out[0,32MiB) (weight staging dead by now)
  attn_kernel<<<dim3(8, 128), 256, 0, stream>>>(rb, kb, vb, attn_kv, faaaa,
                                                out0b, gsum, gsqs);
  gn_stats_kernel<<<1, 128, 0, stream>>>(gsum, gsqs, meaninv);
  ynorm_kernel<<<16384, 256, 0, stream>>>(out0b, gb, meaninv, gamma, beta, yb);

  gemm256_kernel<0, 0><<<dim3(8, 32), 512, 0, stream>>>(yb, wo_t, out_main, HID);

  lastrow_mix_kernel<<<dim3(8, 4), 256, 0, stream>>>(xxx, hidden, w2, tmaa_w, tmaa_k, tmaa_v,
                                                     xw_l, xk_l, xv_l);
  decay1_part_kernel<<<dim3(16, 4), 256, 0, stream>>>(xw_l, tdw1, dpart);
  decay1_reduce_kernel<<<1, 256, 0, stream>>>(dpart, hdec);
  lastrow_kv_part_kernel<<<dim3(8, 16), 256, 0, stream>>>(xk_l, xv_l, keyw, valw, kpart, vpart);
  lastrow_kv_reduce_kernel<<<8, 256, 0, stream>>>(kpart, vpart, hdec, tdw2, tdecay,
                                                  klast, vlast, wlast);
  newkv_kernel<<<2048, 256, 0, stream>>>(klast, vlast, wlast, attn_kv, out_kv);
  copies_kernel<<<32, 256, 0, stream>>>(hidden, ffn_x, out_attnx, out_ffn);
}

// Round 8
// 695.879 us; speedup vs baseline: 1.0158x; 1.0158x over previous
//
#include <hip/hip_runtime.h>

#define HID 2048
#define TSEQ 2048
#define BBATCH 4
#define MROWS 8192   // B*T
#define NHEADS 32

typedef float fvec4 __attribute__((ext_vector_type(4)));
typedef unsigned short usvec4 __attribute__((ext_vector_type(4)));
typedef unsigned short usvec8 __attribute__((ext_vector_type(8)));
typedef __bf16 bh8 __attribute__((ext_vector_type(8)));
typedef float f32x4 __attribute__((ext_vector_type(4)));

__device__ __forceinline__ float bf2f(unsigned short u){
  return __uint_as_float(((unsigned int)u) << 16);
}
__device__ __forceinline__ unsigned short f2bf(float f){
  unsigned int u = __float_as_uint(f);
  return (unsigned short)((u + 0x7fffu + ((u >> 16) & 1u)) >> 16);
}
__device__ __forceinline__ void gll16(const void* g, void* lds){
  __builtin_amdgcn_global_load_lds(
      (const __attribute__((address_space(1))) unsigned int*)g,
      (__attribute__((address_space(3))) unsigned int*)lds, 16, 0, 0);
}

// pipeline sync: counted vmcnt + raw barrier in ONE asm (memory clobber blocks
// IR-level motion) + sched_barrier(0) (blocks MIR scheduler motion) — T4.
#define PIPE_SYNC(NSTR)                                              \
  asm volatile("s_waitcnt vmcnt(" NSTR ")\n\ts_barrier" ::: "memory"); \
  __builtin_amdgcn_sched_barrier(0);

// ---------------- transpose + cast f32 -> bf16 : out[c][r] = in[r][c] -------
__global__ void tcast_kernel(const float* __restrict__ in, unsigned short* __restrict__ out,
                             int R, int C){
  __shared__ float tile[32][33];
  int c0 = blockIdx.x * 32, r0 = blockIdx.y * 32;
  int tx = threadIdx.x, ty = threadIdx.y;
  for (int i = ty; i < 32; i += 8){
    int r = r0 + i, c = c0 + tx;
    tile[i][tx] = (r < R && c < C) ? in[(size_t)r * C + c] : 0.f;
  }
  __syncthreads();
  for (int i = ty; i < 32; i += 8){
    int c = c0 + i, r = r0 + tx;
    if (c < C && r < R) out[(size_t)c * R + r] = f2bf(tile[tx][i]);
  }
}

__global__ void zero_stats_kernel(float* __restrict__ gsum, float* __restrict__ gsqs){
  int i = threadIdx.x;  // 128 threads
  gsum[i] = 0.f;
  gsqs[i] = 0.f;
}

// ---------------- token-shift time_mix -> bf16 ------------------------------
__global__ void tmix_kernel(const float* __restrict__ hidden, const float* __restrict__ attn_x,
                            const float* __restrict__ tmx, unsigned short* __restrict__ tm){
  int i4 = blockIdx.x * 256 + threadIdx.x;        // over MROWS*HID/4
  int row = i4 >> 9;
  int c4 = i4 & 511;
  fvec4 x = *(const fvec4*)&hidden[(size_t)i4 * 4];
  fvec4 p;
  if ((row & (TSEQ - 1)) == 0){
    int b = row >> 11;
    p = *(const fvec4*)&attn_x[b * HID + c4 * 4];
  } else {
    p = *(const fvec4*)&hidden[(size_t)(i4 - 512) * 4];
  }
  fvec4 tx = *(const fvec4*)&tmx[c4 * 4];
  fvec4 t = x + (p - x) * tx;
  usvec4 o;
  o[0]=f2bf(t[0]); o[1]=f2bf(t[1]); o[2]=f2bf(t[2]); o[3]=f2bf(t[3]);
  *(usvec4*)&tm[(size_t)i4 * 4] = o;
}

// ---------------- m97-style bf16 GEMM (kept for the N=160 w1 GEMM) ----------
// ACT: 0 none, 1 tanh, 2 silu.  OUTBF16: store bf16 else f32.
template<int ACT, int OUTBF16>
__global__ __launch_bounds__(256, 2) void gemm_kernel(
    const unsigned short* __restrict__ A, const unsigned short* __restrict__ Bt,
    void* __restrict__ Cptr, int M, int N, int K, int ldc)
{
  __shared__ unsigned short As[128 * 32];
  __shared__ unsigned short Bs[128 * 32];
  const int tid = threadIdx.x;
  const int lane = tid & 63;
  const int w = tid >> 6;
  const int wr = w >> 1, wc = w & 1;
  const int lr = lane & 15, lq = lane >> 4;
  const int rowBase = blockIdx.y * 128;
  const int colBase = blockIdx.x * 128;

  const int arow = tid >> 2;
  const int ach = tid & 3;
  const unsigned short* aptr0 = A + (size_t)(rowBase + arow) * K + ach * 8;
  const unsigned short* aptr1 = aptr0 + (size_t)64 * K;
  int br0 = colBase + arow;      if (br0 > N - 1) br0 = N - 1;
  int br1 = colBase + arow + 64; if (br1 > N - 1) br1 = N - 1;
  const unsigned short* bptr0 = Bt + (size_t)br0 * K + ach * 8;
  const unsigned short* bptr1 = Bt + (size_t)br1 * K + ach * 8;

  f32x4 acc[4][4] = {};

  const int nk = K >> 5;
  for (int kk = 0; kk < nk; ++kk){
    gll16(aptr0, &As[tid * 8]);
    gll16(aptr1, &As[(tid + 256) * 8]);
    gll16(bptr0, &Bs[tid * 8]);
    gll16(bptr1, &Bs[(tid + 256) * 8]);
    aptr0 += 32; aptr1 += 32; bptr0 += 32; bptr1 += 32;
    __syncthreads();
    bh8 af[4], bfv[4];
    #pragma unroll
    for (int m = 0; m < 4; ++m)
      af[m] = *reinterpret_cast<const bh8*>(&As[(wr * 64 + m * 16 + lr) * 32 + lq * 8]);
    #pragma unroll
    for (int n = 0; n < 4; ++n)
      bfv[n] = *reinterpret_cast<const bh8*>(&Bs[(wc * 64 + n * 16 + lr) * 32 + lq * 8]);
    #pragma unroll
    for (int m = 0; m < 4; ++m)
      #pragma unroll
      for (int n = 0; n < 4; ++n)
        acc[m][n] = __builtin_amdgcn_mfma_f32_16x16x32_bf16(af[m], bfv[n], acc[m][n], 0, 0, 0);
    __syncthreads();
  }

  #pragma unroll
  for (int m = 0; m < 4; ++m){
    int gr0 = rowBase + wr * 64 + m * 16 + lq * 4;
    #pragma unroll
    for (int n = 0; n < 4; ++n){
      int gc = colBase + wc * 64 + n * 16 + lr;
      if (gc < N){
        #pragma unroll
        for (int q = 0; q < 4; ++q){
          float v = acc[m][n][q];
          if constexpr (ACT == 1) v = tanhf(v);
          else if constexpr (ACT == 2) v = v / (1.0f + __expf(-v));
          size_t off = (size_t)(gr0 + q) * ldc + gc;
          if constexpr (OUTBF16) ((unsigned short*)Cptr)[off] = f2bf(v);
          else                   ((float*)Cptr)[off] = v;
        }
      }
    }
  }
}

// -- 256x256 bf16 GEMM, BK=32, 4-buffer LDS, counted-vmcnt pipeline (T3+T4) --
// C = A(MxK) * Bt(NxK)^T.  M,N multiples of 256, K multiple of 32 (>=128).
// Swizzle: LDS[r][c] holds global chunk c ^ ((r>>1)&3); read-side per-lane
// constant ksel. XCD-aware block remap (T1): each XCD gets a 4x8 sub-grid.
template<int ACT, int OUTBF16>
__global__ __launch_bounds__(512, 2) void gemm256_kernel(
    const unsigned short* __restrict__ A, const unsigned short* __restrict__ Bt,
    void* __restrict__ Cptr, int K)
{
  __shared__ unsigned short smem[65536];   // 4 buf x (A 8192 + B 8192) elems
  const int tid = threadIdx.x;
  const int lane = tid & 63, w = tid >> 6;
  const int wr = w >> 2, wc = w & 3;           // 2M x 4N waves
  const int lr = lane & 15, lq = lane >> 4;

  // T1: XCD-aware bijective remap (grid 8x32 = 256 blocks = 1/CU)
  const int bid = blockIdx.y * gridDim.x + blockIdx.x;
  const int xcd = bid & 7, qq = bid >> 3;
  const int by = xcd * 4 + (qq >> 3);          // 0..31
  const int bx = qq & 7;                       // 0..7
  const int rowBase = by * 256;
  const int colBase = bx * 256;
  const int N = gridDim.x * 256;               // = ldc

  // staging descriptors: 2 gll A + 2 gll B per K-tile per thread
  const unsigned short* srcA[2]; const unsigned short* srcB[2];
  int dstA[2], dstB[2];
  #pragma unroll
  for (int l = 0; l < 2; ++l){
    int ci = l * 512 + tid;          // 0..1023
    int r = ci >> 2, c = ci & 3;     // row 0..255, chunk 0..3 (8 elems each)
    int g = c ^ ((r >> 1) & 3);      // pre-swizzled global chunk
    srcA[l] = A  + (size_t)(rowBase + r) * K + g * 8;
    srcB[l] = Bt + (size_t)(colBase + r) * K + g * 8;
    dstA[l] = ci * 8;
    dstB[l] = 8192 + ci * 8;
  }

  f32x4 acc[8][4] = {};
  const int ksel = (lq ^ ((lr >> 1) & 3)) * 8;   // per-lane swizzled k-chunk

  auto STAGE = [&](int t, int bi){
    unsigned short* buf = smem + bi * 16384;
    #pragma unroll
    for (int l = 0; l < 2; ++l){
      gll16(srcA[l] + (size_t)t * 32, buf + dstA[l]);
      gll16(srcB[l] + (size_t)t * 32, buf + dstB[l]);
    }
  };

  auto COMPUTE = [&](int bi){
    const unsigned short* aB = smem + bi * 16384;
    const unsigned short* bB = aB + 8192;
    bh8 af[8], bf[4];
    #pragma unroll
    for (int m = 0; m < 8; ++m)
      af[m] = *reinterpret_cast<const bh8*>(&aB[(wr * 128 + m * 16 + lr) * 32 + ksel]);
    #pragma unroll
    for (int n = 0; n < 4; ++n)
      bf[n] = *reinterpret_cast<const bh8*>(&bB[(wc * 64 + n * 16 + lr) * 32 + ksel]);
    __builtin_amdgcn_s_setprio(1);
    #pragma unroll
    for (int m = 0; m < 8; ++m)
      #pragma unroll
      for (int n = 0; n < 4; ++n)
        acc[m][n] = __builtin_amdgcn_mfma_f32_16x16x32_bf16(af[m], bf[n], acc[m][n], 0, 0, 0);
    __builtin_amdgcn_s_setprio(0);
  };

  const int nt = K >> 5;   // >= 4
  // prologue: prefetch tiles 0..2 (12 gll in flight; wait oldest 4 = tile 0)
  STAGE(0, 0); STAGE(1, 1); STAGE(2, 2);
  PIPE_SYNC("8");
  // steady state: stage t+3, compute t, wait tile t+1's loads (vmcnt 12->8)
  for (int t = 0; t < nt - 3; ++t){
    STAGE(t + 3, (t + 3) & 3);
    COMPUTE(t & 3);
    PIPE_SYNC("8");
  }
  COMPUTE((nt - 3) & 3);
  PIPE_SYNC("4");
  COMPUTE((nt - 2) & 3);
  PIPE_SYNC("0");
  COMPUTE((nt - 1) & 3);

  #pragma unroll
  for (int m = 0; m < 8; ++m){
    int gr0 = rowBase + wr * 128 + m * 16 + lq * 4;
    #pragma unroll
    for (int n = 0; n < 4; ++n){
      int gc = colBase + wc * 64 + n * 16 + lr;
      #pragma unroll
      for (int q = 0; q < 4; ++q){
        float v = acc[m][n][q];
        if constexpr (ACT == 1) v = tanhf(v);
        else if constexpr (ACT == 2) v = v / (1.0f + __expf(-v));
        size_t off = (size_t)(gr0 + q) * N + gc;
        if constexpr (OUTBF16) ((unsigned short*)Cptr)[off] = f2bf(v);
        else                   ((float*)Cptr)[off] = v;
      }
    }
  }
}

// ------- einsum(4x K=32) via MFMA + lerp construction of xk/xv/xr/xg --------
__global__ __launch_bounds__(256) void mix_kernel(
    const float* __restrict__ xxx, const float* __restrict__ hidden,
    const float* __restrict__ attn_x, const float* __restrict__ w2,
    const float* __restrict__ tmk, const float* __restrict__ tmv,
    const float* __restrict__ tmr, const float* __restrict__ tmg,
    unsigned short* __restrict__ xk, unsigned short* __restrict__ xv,
    unsigned short* __restrict__ xr, unsigned short* __restrict__ xg)
{
  __shared__ __attribute__((aligned(16))) unsigned short smem[20992];
  unsigned short* xs   = smem;           // [64][168] bf16
  unsigned short* w2t  = smem + 10752;   // [4][64][40] bf16 (w2t[n][cc][j])
  unsigned short* out4 = smem;           // [4][64][72] bf16 (phase B overlay)

  const int tid = threadIdx.x;
  const int r0 = blockIdx.y * 64, c0 = blockIdx.x * 64;
  const int w = tid >> 6, lane = tid & 63, lr = lane & 15, lq = lane >> 4;

  for (int idx = tid; idx < 64 * 40; idx += 256){
    int r = idx / 40, cq = idx - r * 40;
    fvec4 v = *(const fvec4*)&xxx[(size_t)(r0 + r) * 160 + cq * 4];
    usvec4 o;
    o[0]=f2bf(v[0]); o[1]=f2bf(v[1]); o[2]=f2bf(v[2]); o[3]=f2bf(v[3]);
    *(usvec4*)&xs[r * 168 + cq * 4] = o;
  }
  for (int idx = tid; idx < 4 * 32 * 16; idx += 256){
    int n = idx >> 9;
    int rem = idx & 511;
    int j = rem >> 4, cq = rem & 15;
    fvec4 v = *(const fvec4*)&w2[(size_t)((n + 1) * 32 + j) * HID + c0 + cq * 4];
    #pragma unroll
    for (int cc = 0; cc < 4; ++cc)
      w2t[(n * 64 + cq * 4 + cc) * 40 + j] = f2bf(v[cc]);
  }
  __syncthreads();

  f32x4 acc[4][4] = {};
  #pragma unroll
  for (int n = 0; n < 4; ++n){
    bh8 afr = *reinterpret_cast<const bh8*>(&xs[(w * 16 + lr) * 168 + (n + 1) * 32 + lq * 8]);
    #pragma unroll
    for (int ct = 0; ct < 4; ++ct){
      bh8 bfr = *reinterpret_cast<const bh8*>(&w2t[(n * 64 + ct * 16 + lr) * 40 + lq * 8]);
      acc[ct][n] = __builtin_amdgcn_mfma_f32_16x16x32_bf16(afr, bfr, acc[ct][n], 0, 0, 0);
    }
  }
  __syncthreads();

  #pragma unroll
  for (int ct = 0; ct < 4; ++ct){
    int gc = c0 + ct * 16 + lr;
    float tk_ = tmk[gc], tv_ = tmv[gc], tr_ = tmr[gc], tg_ = tmg[gc];
    #pragma unroll
    for (int q = 0; q < 4; ++q){
      int row64 = w * 16 + lq * 4 + q;
      int gr = r0 + row64;
      size_t rowoff = (size_t)gr * HID + gc;
      float xx = hidden[rowoff];
      float pp = ((gr & (TSEQ - 1)) == 0) ? attn_x[(gr >> 11) * HID + gc]
                                          : hidden[rowoff - HID];
      float dxv = pp - xx;
      int lo = row64 * 72 + ct * 16 + lr;
      out4[(0 * 64 * 72) + lo] = f2bf(xx + dxv * (tk_ + acc[ct][0][q]));
      out4[(1 * 64 * 72) + lo] = f2bf(xx + dxv * (tv_ + acc[ct][1][q]));
      out4[(2 * 64 * 72) + lo] = f2bf(xx + dxv * (tr_ + acc[ct][2][q]));
      out4[(3 * 64 * 72) + lo] = f2bf(xx + dxv * (tg_ + acc[ct][3][q]));
    }
  }
  __syncthreads();

  #pragma unroll
  for (int a = 0; a < 4; ++a){
    unsigned short* dst = (a == 0) ? xk : (a == 1) ? xv : (a == 2) ? xr : xg;
    #pragma unroll
    for (int pass = 0; pass < 2; ++pass){
      int row64 = pass * 32 + (tid >> 3);
      int c8 = (tid & 7) * 8;
      usvec8 v8 = *(const usvec8*)&out4[(a * 64 + row64) * 72 + c8];
      *(usvec8*)&dst[(size_t)(r0 + row64) * HID + c0 + c8] = v8;
    }
  }
}

// --------- attention via MFMA: out0 = r@akv + rk*v ; group stats ------------
__global__ __launch_bounds__(256) void attn_kernel(
    const unsigned short* __restrict__ rb, const unsigned short* __restrict__ kb,
    const unsigned short* __restrict__ vb, const float* __restrict__ attn_kv,
    const float* __restrict__ faaaa, unsigned short* __restrict__ out0b,
    float* __restrict__ gsum, float* __restrict__ gsqs)
{
  const int bh = blockIdx.y;           // 128 = b*32+h
  const int b = bh >> 5, h = bh & 31;
  const int tid = threadIdx.x, lane = tid & 63, w = tid >> 6;
  const int lr = lane & 15, lq = lane >> 4;
  const int t0 = blockIdx.x * 256 + w * 64;
  const size_t rowbase = (size_t)(b * TSEQ + t0) * HID + h * 64;

  const float* akvp = attn_kv + (size_t)bh * 4096;
  bh8 bfr[2][4];
  #pragma unroll
  for (int kk = 0; kk < 2; ++kk)
    #pragma unroll
    for (int n = 0; n < 4; ++n)
      #pragma unroll
      for (int j = 0; j < 8; ++j)
        bfr[kk][n][j] = (__bf16)akvp[(kk * 32 + lq * 8 + j) * 64 + n * 16 + lr];

  float fa0[8], fa1[8];
  #pragma unroll
  for (int j = 0; j < 8; ++j){
    fa0[j] = faaaa[h * 64 + lq * 8 + j];
    fa1[j] = faaaa[h * 64 + 32 + lq * 8 + j];
  }

  __shared__ __attribute__((aligned(16))) float rk_s[4][64];
  __shared__ __attribute__((aligned(16))) unsigned short outb[4][64][72];

  f32x4 acc[4][4] = {};
  #pragma unroll
  for (int m = 0; m < 4; ++m){
    size_t ra = rowbase + (size_t)(m * 16 + lr) * HID;
    bh8 a0 = *reinterpret_cast<const bh8*>(&rb[ra + lq * 8]);
    bh8 a1 = *reinterpret_cast<const bh8*>(&rb[ra + 32 + lq * 8]);
    usvec8 k0 = *reinterpret_cast<const usvec8*>(&kb[ra + lq * 8]);
    usvec8 k1 = *reinterpret_cast<const usvec8*>(&kb[ra + 32 + lq * 8]);
    float p = 0.f;
    #pragma unroll
    for (int j = 0; j < 8; ++j){
      p += (float)a0[j] * fa0[j] * bf2f(k0[j]);
      p += (float)a1[j] * fa1[j] * bf2f(k1[j]);
    }
    p += __shfl_xor(p, 16, 64);
    p += __shfl_xor(p, 32, 64);
    if (lq == 0) rk_s[w][m * 16 + lr] = p;
    #pragma unroll
    for (int n = 0; n < 4; ++n){
      acc[m][n] = __builtin_amdgcn_mfma_f32_16x16x32_bf16(a0, bfr[0][n], acc[m][n], 0, 0, 0);
      acc[m][n] = __builtin_amdgcn_mfma_f32_16x16x32_bf16(a1, bfr[1][n], acc[m][n], 0, 0, 0);
    }
  }
  __syncthreads();

  float ssum = 0.f, ssq = 0.f;
  #pragma unroll
  for (int m = 0; m < 4; ++m){
    fvec4 rk4 = *(const fvec4*)&rk_s[w][m * 16 + lq * 4];
    #pragma unroll
    for (int n = 0; n < 4; ++n){
      int col = n * 16 + lr;
      #pragma unroll
      for (int q = 0; q < 4; ++q){
        int row = m * 16 + lq * 4 + q;
        float vv = bf2f(vb[rowbase + (size_t)row * HID + col]);
        float o = acc[m][n][q] + rk4[q] * vv;
        ssum += o; ssq += o * o;
        outb[w][row][col] = f2bf(o);
      }
    }
  }
  __syncthreads();
  #pragma unroll
  for (int pass = 0; pass < 8; ++pass){
    int row = pass * 8 + (lane >> 3);
    int c8 = (lane & 7) * 8;
    usvec8 o8 = *(const usvec8*)&outb[w][row][c8];
    *(usvec8*)&out0b[rowbase + (size_t)row * HID + c8] = o8;
  }
  #pragma unroll
  for (int off2 = 32; off2 > 0; off2 >>= 1){
    ssum += __shfl_xor(ssum, off2, 64);
    ssq  += __shfl_xor(ssq,  off2, 64);
  }
  if (lane == 0){ atomicAdd(&gsum[bh], ssum); atomicAdd(&gsqs[bh], ssq); }
}

__global__ void gn_stats_kernel(const float* __restrict__ gsum, const float* __restrict__ gsqs,
                                float* __restrict__ meaninv){
  int g = threadIdx.x;  // 128 groups
  const float n = (float)(TSEQ * 64);
  float mean = gsum[g] / n;
  float var = gsqs[g] / n - mean * mean;
  meaninv[2 * g]     = mean;
  meaninv[2 * g + 1] = rsqrtf(var + 1e-5f * 64.0f * 64.0f);
}

__global__ void ynorm_kernel(const unsigned short* __restrict__ out0b,
                             const unsigned short* __restrict__ gb,
                             const float* __restrict__ meaninv, const float* __restrict__ gamma,
                             const float* __restrict__ beta, unsigned short* __restrict__ yb){
  int i4 = blockIdx.x * 256 + threadIdx.x;
  int row = i4 >> 9, c4 = i4 & 511;
  int b = row >> 11;
  int c = c4 * 4;
  int g = b * 32 + (c >> 6);
  float mean = meaninv[2 * g], inv = meaninv[2 * g + 1];
  usvec4 o4 = *(const usvec4*)&out0b[(size_t)i4 * 4];
  usvec4 gv = *(const usvec4*)&gb[(size_t)i4 * 4];
  fvec4 ga = *(const fvec4*)&gamma[c];
  fvec4 be = *(const fvec4*)&beta[c];
  usvec4 y;
  #pragma unroll
  for (int cc = 0; cc < 4; ++cc){
    float val = ((bf2f(o4[cc]) - mean) * inv * ga[cc] + be[cc]) * bf2f(gv[cc]);
    y[cc] = f2bf(val);
  }
  *(usvec4*)&yb[(size_t)i4 * 4] = y;
}

// ---------------- exact f32 last-row path (w / k_last / v_last) -------------
__global__ void lastrow_mix_kernel(const float* __restrict__ xxx, const float* __restrict__ hidden,
    const float* __restrict__ w2, const float* __restrict__ tmw, const float* __restrict__ tmk,
    const float* __restrict__ tmv, float* __restrict__ xw_l, float* __restrict__ xk_l,
    float* __restrict__ xv_l){
  int b = blockIdx.y;
  int c = blockIdx.x * 256 + threadIdx.x;
  __shared__ float xsr[160];
  int i = b * TSEQ + (TSEQ - 1);
  if (threadIdx.x < 160) xsr[threadIdx.x] = xxx[(size_t)i * 160 + threadIdx.x];
  __syncthreads();
  float mw = 0.f, mk = 0.f, mv = 0.f;
  for (int j = 0; j < 32; ++j){
    mw += xsr[j]      * w2[(size_t)(j)      * HID + c];
    mk += xsr[32 + j] * w2[(size_t)(32 + j) * HID + c];
    mv += xsr[64 + j] * w2[(size_t)(64 + j) * HID + c];
  }
  float x = hidden[(size_t)i * HID + c];
  float prev = hidden[(size_t)(i - 1) * HID + c];
  float dx = prev - x;
  xw_l[b * HID + c] = x + dx * (tmw[c] + mw);
  xk_l[b * HID + c] = x + dx * (tmk[c] + mk);
  xv_l[b * HID + c] = x + dx * (tmv[c] + mv);
}

// ---- decay: hdec[b][j] = tanh(sum_c xw_l[b][c]*tdw1[c][j]) — split+reduce --
__global__ void decay1_part_kernel(const float* __restrict__ xw_l, const float* __restrict__ tdw1,
                                   float* __restrict__ dpart){
  int b = blockIdx.y;           // 4
  int chunk = blockIdx.x;       // 16 chunks of 128 c-rows
  int j = threadIdx.x & 63, sub = threadIdx.x >> 6;   // 4 subs x 32 rows
  float s = 0.f;
  int cbase = chunk * 128 + sub * 32;
  for (int r = 0; r < 32; ++r){
    int c = cbase + r;
    s += xw_l[b * HID + c] * tdw1[(size_t)c * 64 + j];
  }
  __shared__ float red[4][64];
  red[sub][j] = s;
  __syncthreads();
  if (sub == 0)
    dpart[((size_t)b * 16 + chunk) * 64 + j] = red[0][j] + red[1][j] + red[2][j] + red[3][j];
}

__global__ void decay1_reduce_kernel(const float* __restrict__ dpart, float* __restrict__ hdec){
  int tid = threadIdx.x;        // 256 = 4 b x 64 j
  int b = tid >> 6, j = tid & 63;
  float s = 0.f;
  #pragma unroll
  for (int chunk = 0; chunk < 16; ++chunk)
    s += dpart[((size_t)b * 16 + chunk) * 64 + j];
  hdec[b * 64 + j] = tanhf(s);
}

// ---- last-row k/v GEMVs: k-chunked partials (wide grid) + reduce -----------
__global__ __launch_bounds__(256) void lastrow_kv_part_kernel(
    const float* __restrict__ xk_l, const float* __restrict__ xv_l,
    const float* __restrict__ keyw, const float* __restrict__ valw,
    float* __restrict__ kpart, float* __restrict__ vpart){
  int c = blockIdx.x * 256 + threadIdx.x;   // 8 blocks -> 2048 cols
  int chunk = blockIdx.y;                   // 16 chunks of 128 rows
  __shared__ float xs[2][4][128];
  for (int i = threadIdx.x; i < 512; i += 256){
    int b = i >> 7, r = i & 127;
    xs[0][b][r] = xk_l[b * HID + chunk * 128 + r];
    xs[1][b][r] = xv_l[b * HID + chunk * 128 + r];
  }
  __syncthreads();
  float ka[4] = {0,0,0,0}, va[4] = {0,0,0,0};
  for (int r = 0; r < 128; ++r){
    int c2 = chunk * 128 + r;
    float kw = keyw[(size_t)c2 * HID + c];
    float vw = valw[(size_t)c2 * HID + c];
    #pragma unroll
    for (int b = 0; b < 4; ++b){
      ka[b] += xs[0][b][r] * kw;
      va[b] += xs[1][b][r] * vw;
    }
  }
  #pragma unroll
  for (int b = 0; b < 4; ++b){
    kpart[((size_t)chunk * 4 + b) * HID + c] = ka[b];
    vpart[((size_t)chunk * 4 + b) * HID + c] = va[b];
  }
}

__global__ void lastrow_kv_reduce_kernel(
    const float* __restrict__ kpart, const float* __restrict__ vpart,
    const float* __restrict__ hdec, const float* __restrict__ tdw2,
    const float* __restrict__ tdecay, float* __restrict__ klast,
    float* __restrict__ vlast, float* __restrict__ wlast){
  int c = blockIdx.x * 256 + threadIdx.x;   // 8 blocks -> 2048 cols
  float ka[4] = {0,0,0,0}, va[4] = {0,0,0,0};
  for (int chunk = 0; chunk < 16; ++chunk){
    #pragma unroll
    for (int b = 0; b < 4; ++b){
      ka[b] += kpart[((size_t)chunk * 4 + b) * HID + c];
      va[b] += vpart[((size_t)chunk * 4 + b) * HID + c];
    }
  }
  float tdc = tdecay[c];
  float td[4] = {tdc, tdc, tdc, tdc};
  for (int j = 0; j < 64; ++j){
    float w2v = tdw2[(size_t)j * HID + c];
    #pragma unroll
    for (int b = 0; b < 4; ++b) td[b] += hdec[b * 64 + j] * w2v;
  }
  #pragma unroll
  for (int b = 0; b < 4; ++b){
    klast[b * HID + c] = ka[b];
    vlast[b * HID + c] = va[b];
    wlast[b * HID + c] = expf(-expf(td[b]));
  }
}

__global__ void newkv_kernel(const float* __restrict__ klast, const float* __restrict__ vlast,
    const float* __restrict__ wlast, const float* __restrict__ attn_kv,
    float* __restrict__ outkv){
  int idx = blockIdx.x * 256 + threadIdx.x;  // < 524288
  int b = idx >> 17;
  int h = (idx >> 12) & 31;
  int d = (idx >> 6) & 63;
  int e = idx & 63;
  float kl = klast[b * HID + h * 64 + d];
  float vl = vlast[b * HID + h * 64 + e];
  float wl = wlast[b * HID + h * 64 + d];
  outkv[idx] = kl * vl + wl * attn_kv[idx];
}

__global__ void copies_kernel(const float* __restrict__ hidden, const float* __restrict__ ffnx,
                              float* __restrict__ out_attnx, float* __restrict__ out_ffnx){
  int i = blockIdx.x * 256 + threadIdx.x;
  if (i < BBATCH * HID){
    int b = i >> 11, c = i & 2047;
    out_attnx[i] = hidden[((size_t)(b * TSEQ + TSEQ - 1)) * HID + c];
    out_ffnx[i] = ffnx[i];
  }
}

// ---------------------------------------------------------------------------
extern "C" void kernel_launch(void* const* d_in, const int* in_sizes, int n_in,
                              void* d_out, int out_size, void* d_ws, size_t ws_size,
                              hipStream_t stream)
{
  (void)in_sizes; (void)n_in; (void)out_size;
  const float* hidden = (const float*)d_in[0];
  const float* attn_x = (const float*)d_in[1];
  const float* attn_kv = (const float*)d_in[2];
  const float* ffn_x = (const float*)d_in[3];
  const float* tmaa_x = (const float*)d_in[4];
  const float* tmaa_w = (const float*)d_in[5];
  const float* tmaa_k = (const float*)d_in[6];
  const float* tmaa_v = (const float*)d_in[7];
  const float* tmaa_r = (const float*)d_in[8];
  const float* tmaa_g = (const float*)d_in[9];
  const float* w1 = (const float*)d_in[10];
  const float* w2 = (const float*)d_in[11];
  const float* tdecay = (const float*)d_in[12];
  const float* tdw1 = (const float*)d_in[13];
  const float* tdw2 = (const float*)d_in[14];
  const float* faaaa = (const float*)d_in[15];
  const float* recw = (const float*)d_in[16];
  const float* keyw = (const float*)d_in[17];
  const float* valw = (const float*)d_in[18];
  const float* gatew = (const float*)d_in[19];
  const float* outw = (const float*)d_in[20];
  const float* gamma = (const float*)d_in[21];
  const float* beta = (const float*)d_in[22];

  // output segments (all f32): out | new_attn_x | new_attn_kv | ffn_x
  float* out_main  = (float*)d_out;
  float* out_attnx = out_main + (size_t)16777216;
  float* out_kv    = out_attnx + 8192;
  float* out_ffn   = out_kv + 524288;

  // Early scratch inside d_out (finalized only by the last GEMM):
  //  phase 1 (GEMMs): 4 transposed bf16 weights in [0,32MiB)
  //  phase 2 (attn..ynorm): bf16 out0 in [0,32MiB)
  unsigned short* wr_t = (unsigned short*)d_out;              // 2048x2048 bf16
  unsigned short* wk_t = wr_t + (size_t)4194304;
  unsigned short* wv_t = wk_t + (size_t)4194304;
  unsigned short* wg_t = wv_t + (size_t)4194304;              // ends at 32 MiB
  unsigned short* out0b = (unsigned short*)d_out;             // MROWS*HID bf16

  // workspace layout (~175 MiB), liveness-aliased big buffers:
  //   A: tm -> xg   B: xr -> kb -> yb   C: xk -> vb   D: xv -> gb   E: rb
  char* ws = (char*)d_ws;
  size_t off = 0;
  auto alloc = [&](size_t bytes) -> void* {
    void* p = ws + off; off += (bytes + 255) & ~(size_t)255; return p;
  };
  unsigned short* wo_t = (unsigned short*)alloc(2048ull * 2048 * 2);
  unsigned short* w1_t = (unsigned short*)alloc(160ull * 2048 * 2);
  float* xxx           = (float*)alloc((size_t)MROWS * 160 * 4);
  unsigned short* bufA = (unsigned short*)alloc((size_t)MROWS * HID * 2);
  unsigned short* bufB = (unsigned short*)alloc((size_t)MROWS * HID * 2);
  unsigned short* bufC = (unsigned short*)alloc((size_t)MROWS * HID * 2);
  unsigned short* bufD = (unsigned short*)alloc((size_t)MROWS * HID * 2);
  unsigned short* bufE = (unsigned short*)alloc((size_t)MROWS * HID * 2);
  float* gsum    = (float*)alloc(128 * 4);
  float* gsqs    = (float*)alloc(128 * 4);
  float* meaninv = (float*)alloc(256 * 4);
  float* xw_l  = (float*)alloc(BBATCH * HID * 4);
  float* xk_l  = (float*)alloc(BBATCH * HID * 4);
  float* xv_l  = (float*)alloc(BBATCH * HID * 4);
  float* klast = (float*)alloc(BBATCH * HID * 4);
  float* vlast = (float*)alloc(BBATCH * HID * 4);
  float* wlast = (float*)alloc(BBATCH * HID * 4);
  float* hdec  = (float*)alloc(BBATCH * 64 * 4);
  float* kpart = (float*)alloc(16ull * BBATCH * HID * 4);
  float* vpart = (float*)alloc(16ull * BBATCH * HID * 4);
  float* dpart = (float*)alloc((size_t)BBATCH * 16 * 64 * 4);

  if (off > ws_size) return;   // diagnostic: ws too small -> clean absmax fail

  unsigned short* tm = bufA;   // live: tmix .. w1-GEMM
  unsigned short* xg = bufA;   // live: mix .. g-GEMM
  unsigned short* xr = bufB;   // live: mix .. r-GEMM
  unsigned short* kb = bufB;   // live: k-GEMM .. attn
  unsigned short* yb = bufB;   // live: ynorm .. out-GEMM
  unsigned short* xk = bufC;   // live: mix .. k-GEMM
  unsigned short* vb = bufC;   // live: v-GEMM .. attn
  unsigned short* xv = bufD;   // live: mix .. v-GEMM
  unsigned short* gb = bufD;   // live: g-GEMM .. ynorm
  unsigned short* rb = bufE;   // live: r-GEMM .. attn

  dim3 tb(32, 8);
  tcast_kernel<<<dim3(64, 64), tb, 0, stream>>>(recw,  wr_t, 2048, 2048);
  tcast_kernel<<<dim3(64, 64), tb, 0, stream>>>(keyw,  wk_t, 2048, 2048);
  tcast_kernel<<<dim3(64, 64), tb, 0, stream>>>(valw,  wv_t, 2048, 2048);
  tcast_kernel<<<dim3(64, 64), tb, 0, stream>>>(gatew, wg_t, 2048, 2048);
  tcast_kernel<<<dim3(64, 64), tb, 0, stream>>>(outw,  wo_t, 2048, 2048);
  tcast_kernel<<<dim3(5, 64),  tb, 0, stream>>>(w1,    w1_t, 2048, 160);
  zero_stats_kernel<<<1, 128, 0, stream>>>(gsum, gsqs);

  tmix_kernel<<<16384, 256, 0, stream>>>(hidden, attn_x, tmaa_x, tm);

  gemm_kernel<1, 0><<<dim3(2, 64), 256, 0, stream>>>(tm, w1_t, xxx, MROWS, 160, HID, 160);

  mix_kernel<<<dim3(32, 128), 256, 0, stream>>>(xxx, hidden, attn_x, w2,
      tmaa_k, tmaa_v, tmaa_r, tmaa_g, xk, xv, xr, xg);

  // big GEMMs: 256^2 tile, counted-vmcnt pipeline, grid 8x32 = 256 blocks
  gemm256_kernel<0, 1><<<dim3(8, 32), 512, 0, stream>>>(xr, wr_t, rb, HID);
  gemm256_kernel<0, 1><<<dim3(8, 32), 512, 0, stream>>>(xk, wk_t, kb, HID);
  gemm256_kernel<0, 1><<<dim3(8, 32), 512, 0, stream>>>(xv, wv_t, vb, HID);
  gemm256_kernel<2, 1><<<dim3(8, 32), 512, 0, stream>>>(xg, wg_t, gb, HID);

  // attn writes bf16 out0 over d_out[0,32MiB) (weight staging dead by now)
  attn_kernel<<<dim3(8, 128), 256, 0, stream>>>(rb, kb, vb, attn_kv, faaaa,
                                                out0b, gsum, gsqs);
  gn_stats_kernel<<<1, 128, 0, stream>>>(gsum, gsqs, meaninv);
  ynorm_kernel<<<16384, 256, 0, stream>>>(out0b, gb, meaninv, gamma, beta, yb);

  gemm256_kernel<0, 0><<<dim3(8, 32), 512, 0, stream>>>(yb, wo_t, out_main, HID);

  lastrow_mix_kernel<<<dim3(8, 4), 256, 0, stream>>>(xxx, hidden, w2, tmaa_w, tmaa_k, tmaa_v,
                                                     xw_l, xk_l, xv_l);
  decay1_part_kernel<<<dim3(16, 4), 256, 0, stream>>>(xw_l, tdw1, dpart);
  decay1_reduce_kernel<<<1, 256, 0, stream>>>(dpart, hdec);
  lastrow_kv_part_kernel<<<dim3(8, 16), 256, 0, stream>>>(xk_l, xv_l, keyw, valw, kpart, vpart);
  lastrow_kv_reduce_kernel<<<8, 256, 0, stream>>>(kpart, vpart, hdec, tdw2, tdecay,
                                                  klast, vlast, wlast);
  newkv_kernel<<<2048, 256, 0, stream>>>(klast, vlast, wlast, attn_kv, out_kv);
  copies_kernel<<<32, 256, 0, stream>>>(hidden, ffn_x, out_attnx, out_ffn);
}

// Round 9
// 690.324 us; speedup vs baseline: 1.0239x; 1.0080x over previous
//
#include <hip/hip_runtime.h>

#define HID 2048
#define TSEQ 2048
#define BBATCH 4
#define MROWS 8192   // B*T
#define NHEADS 32

typedef float fvec4 __attribute__((ext_vector_type(4)));
typedef unsigned short usvec4 __attribute__((ext_vector_type(4)));
typedef unsigned short usvec8 __attribute__((ext_vector_type(8)));
typedef __bf16 bh8 __attribute__((ext_vector_type(8)));
typedef float f32x4 __attribute__((ext_vector_type(4)));

__device__ __forceinline__ float bf2f(unsigned short u){
  return __uint_as_float(((unsigned int)u) << 16);
}
__device__ __forceinline__ unsigned short f2bf(float f){
  unsigned int u = __float_as_uint(f);
  return (unsigned short)((u + 0x7fffu + ((u >> 16) & 1u)) >> 16);
}
__device__ __forceinline__ void gll16(const void* g, void* lds){
  __builtin_amdgcn_global_load_lds(
      (const __attribute__((address_space(1))) unsigned int*)g,
      (__attribute__((address_space(3))) unsigned int*)lds, 16, 0, 0);
}

// ---------------- transpose + cast f32 -> bf16 : out[c][r] = in[r][c] -------
__global__ void tcast_kernel(const float* __restrict__ in, unsigned short* __restrict__ out,
                             int R, int C){
  __shared__ float tile[32][33];
  int c0 = blockIdx.x * 32, r0 = blockIdx.y * 32;
  int tx = threadIdx.x, ty = threadIdx.y;
  for (int i = ty; i < 32; i += 8){
    int r = r0 + i, c = c0 + tx;
    tile[i][tx] = (r < R && c < C) ? in[(size_t)r * C + c] : 0.f;
  }
  __syncthreads();
  for (int i = ty; i < 32; i += 8){
    int c = c0 + i, r = r0 + tx;
    if (c < C && r < R) out[(size_t)c * R + r] = f2bf(tile[tx][i]);
  }
}

// 5 fixed 2048x2048 weight transposes in ONE dispatch (grid.z selects)
__global__ void tcast5_kernel(const float* __restrict__ i0, const float* __restrict__ i1,
                              const float* __restrict__ i2, const float* __restrict__ i3,
                              const float* __restrict__ i4,
                              unsigned short* __restrict__ o0, unsigned short* __restrict__ o1,
                              unsigned short* __restrict__ o2, unsigned short* __restrict__ o3,
                              unsigned short* __restrict__ o4){
  const float* in; unsigned short* out;
  switch (blockIdx.z){
    case 0:  in = i0; out = o0; break;
    case 1:  in = i1; out = o1; break;
    case 2:  in = i2; out = o2; break;
    case 3:  in = i3; out = o3; break;
    default: in = i4; out = o4; break;
  }
  __shared__ float tile[32][33];
  int c0 = blockIdx.x * 32, r0 = blockIdx.y * 32;
  int tx = threadIdx.x, ty = threadIdx.y;
  for (int i = ty; i < 32; i += 8)
    tile[i][tx] = in[(size_t)(r0 + i) * 2048 + c0 + tx];
  __syncthreads();
  for (int i = ty; i < 32; i += 8)
    out[(size_t)(c0 + i) * 2048 + r0 + tx] = f2bf(tile[tx][i]);
}

__global__ void zero_stats_kernel(float* __restrict__ gsum, float* __restrict__ gsqs){
  int i = threadIdx.x;  // 128 threads
  gsum[i] = 0.f;
  gsqs[i] = 0.f;
}

// ---------------- token-shift time_mix -> bf16 ------------------------------
__global__ void tmix_kernel(const float* __restrict__ hidden, const float* __restrict__ attn_x,
                            const float* __restrict__ tmx, unsigned short* __restrict__ tm){
  int i4 = blockIdx.x * 256 + threadIdx.x;        // over MROWS*HID/4
  int row = i4 >> 9;
  int c4 = i4 & 511;
  fvec4 x = *(const fvec4*)&hidden[(size_t)i4 * 4];
  fvec4 p;
  if ((row & (TSEQ - 1)) == 0){
    int b = row >> 11;
    p = *(const fvec4*)&attn_x[b * HID + c4 * 4];
  } else {
    p = *(const fvec4*)&hidden[(size_t)(i4 - 512) * 4];
  }
  fvec4 tx = *(const fvec4*)&tmx[c4 * 4];
  fvec4 t = x + (p - x) * tx;
  usvec4 o;
  o[0]=f2bf(t[0]); o[1]=f2bf(t[1]); o[2]=f2bf(t[2]); o[3]=f2bf(t[3]);
  *(usvec4*)&tm[(size_t)i4 * 4] = o;
}

// ---------------- m97-style bf16 GEMM (kept for the N=160 w1 GEMM) ----------
// ACT: 0 none, 1 tanh, 2 silu.  OUTBF16: store bf16 else f32.
template<int ACT, int OUTBF16>
__global__ __launch_bounds__(256, 2) void gemm_kernel(
    const unsigned short* __restrict__ A, const unsigned short* __restrict__ Bt,
    void* __restrict__ Cptr, int M, int N, int K, int ldc)
{
  __shared__ unsigned short As[128 * 32];
  __shared__ unsigned short Bs[128 * 32];
  const int tid = threadIdx.x;
  const int lane = tid & 63;
  const int w = tid >> 6;
  const int wr = w >> 1, wc = w & 1;
  const int lr = lane & 15, lq = lane >> 4;
  const int rowBase = blockIdx.y * 128;
  const int colBase = blockIdx.x * 128;

  const int arow = tid >> 2;
  const int ach = tid & 3;
  const unsigned short* aptr0 = A + (size_t)(rowBase + arow) * K + ach * 8;
  const unsigned short* aptr1 = aptr0 + (size_t)64 * K;
  int br0 = colBase + arow;      if (br0 > N - 1) br0 = N - 1;
  int br1 = colBase + arow + 64; if (br1 > N - 1) br1 = N - 1;
  const unsigned short* bptr0 = Bt + (size_t)br0 * K + ach * 8;
  const unsigned short* bptr1 = Bt + (size_t)br1 * K + ach * 8;

  f32x4 acc[4][4] = {};

  const int nk = K >> 5;
  for (int kk = 0; kk < nk; ++kk){
    gll16(aptr0, &As[tid * 8]);
    gll16(aptr1, &As[(tid + 256) * 8]);
    gll16(bptr0, &Bs[tid * 8]);
    gll16(bptr1, &Bs[(tid + 256) * 8]);
    aptr0 += 32; aptr1 += 32; bptr0 += 32; bptr1 += 32;
    __syncthreads();
    bh8 af[4], bfv[4];
    #pragma unroll
    for (int m = 0; m < 4; ++m)
      af[m] = *reinterpret_cast<const bh8*>(&As[(wr * 64 + m * 16 + lr) * 32 + lq * 8]);
    #pragma unroll
    for (int n = 0; n < 4; ++n)
      bfv[n] = *reinterpret_cast<const bh8*>(&Bs[(wc * 64 + n * 16 + lr) * 32 + lq * 8]);
    #pragma unroll
    for (int m = 0; m < 4; ++m)
      #pragma unroll
      for (int n = 0; n < 4; ++n)
        acc[m][n] = __builtin_amdgcn_mfma_f32_16x16x32_bf16(af[m], bfv[n], acc[m][n], 0, 0, 0);
    __syncthreads();
  }

  #pragma unroll
  for (int m = 0; m < 4; ++m){
    int gr0 = rowBase + wr * 64 + m * 16 + lq * 4;
    #pragma unroll
    for (int n = 0; n < 4; ++n){
      int gc = colBase + wc * 64 + n * 16 + lr;
      if (gc < N){
        #pragma unroll
        for (int q = 0; q < 4; ++q){
          float v = acc[m][n][q];
          if constexpr (ACT == 1) v = tanhf(v);
          else if constexpr (ACT == 2) v = v / (1.0f + __expf(-v));
          size_t off = (size_t)(gr0 + q) * ldc + gc;
          if constexpr (OUTBF16) ((unsigned short*)Cptr)[off] = f2bf(v);
          else                   ((float*)Cptr)[off] = v;
        }
      }
    }
  }
}

// ---- 256x256 bf16 GEMM, 8-phase schedule (m201 port, plain HIP) ------------
// C = A(MxK) * Bt(NxK)^T.  M,N mult of 256, K mult of 64 (>=128), ldc=N.
// Half-tile = one matrix x 256 rows x 32 k (16 KB, 2 gll/thread). 8 rotating
// LDS slots (128 KiB). Stage distance: phase p stages half p+5; vmcnt(6) at
// odd phases guarantees next pair's halves landed (3 halves max in flight).
// Phase: {stage, ds_read(10|2), s_barrier, lgkmcnt(0), setprio1, 16 MFMA,
// setprio0, barrier[/vmcnt(6)]}. Per-lane-constant swizzle ksel (2-way free).
template<int ACT, int OUTBF16>
__global__ __launch_bounds__(512, 2) void gemm256_kernel(
    const unsigned short* __restrict__ A, const unsigned short* __restrict__ Bt,
    void* __restrict__ Cptr, int K)
{
  __shared__ unsigned short smem[65536];   // 8 half-slots x 8192 elems
  const int tid = threadIdx.x;
  const int lane = tid & 63, w = tid >> 6;
  const int wr = w >> 2, wc = w & 3;           // 2M x 4N waves
  const int lr = lane & 15, lq = lane >> 4;

  // T1: XCD-aware bijective remap (grid 8x32 = 256 blocks = 1/CU)
  const int bid = blockIdx.y * gridDim.x + blockIdx.x;
  const int xcd = bid & 7, qq = bid >> 3;
  const int by = xcd * 4 + (qq >> 3);
  const int bx = qq & 7;
  const int rowBase = by * 256;
  const int colBase = bx * 256;
  const int N = gridDim.x * 256;               // = ldc

  // staging: thread covers ci = ld*512+tid -> r=ci>>2 (0..255), c=ci&3
  const unsigned short* gA[2]; const unsigned short* gB[2];
  int dstoff[2];
  #pragma unroll
  for (int ld = 0; ld < 2; ++ld){
    int ci = ld * 512 + tid;
    int r = ci >> 2, c = ci & 3;
    int g = c ^ ((r >> 1) & 3);      // pre-swizzled global chunk
    gA[ld] = A  + (size_t)(rowBase + r) * K + g * 8;
    gB[ld] = Bt + (size_t)(colBase + r) * K + g * 8;
    dstoff[ld] = ci * 8;             // linear LDS dest (wave-uniform + lane*16)
  }

  f32x4 acc[8][4] = {};
  bh8 af[8], bfr[2];
  const int ksel = (lq ^ ((lr >> 1) & 3)) * 8;   // read-side swizzle, per-lane const

  auto STAGE = [&](int h){
    int koff = (h >> 2) * 64 + ((h >> 1) & 1) * 32;
    unsigned short* sb = smem + (h & 7) * 8192;
    if (h & 1){
      gll16(gB[0] + koff, sb + dstoff[0]);
      gll16(gB[1] + koff, sb + dstoff[1]);
    } else {
      gll16(gA[0] + koff, sb + dstoff[0]);
      gll16(gA[1] + koff, sb + dstoff[1]);
    }
  };
  auto RDA = [&](const unsigned short* aB){
    #pragma unroll
    for (int m = 0; m < 8; ++m){
      int row = wr * 128 + m * 16 + lr;
      af[m] = *reinterpret_cast<const bh8*>(&aB[row * 32 + ksel]);
    }
  };
  auto RDB = [&](const unsigned short* bB, int nh){
    #pragma unroll
    for (int i = 0; i < 2; ++i){
      int row = wc * 64 + (nh * 2 + i) * 16 + lr;
      bfr[i] = *reinterpret_cast<const bh8*>(&bB[row * 32 + ksel]);
    }
  };

  const int nph = K >> 4;   // total phases (4 per 64-K tile)

  // prologue: stage halves 0..4 (10 loads); vmcnt(6) -> halves 0,1 landed
  STAGE(0); STAGE(1); STAGE(2); STAGE(3); STAGE(4);
  asm volatile("s_waitcnt vmcnt(6)\n\ts_barrier" ::: "memory");
  __builtin_amdgcn_sched_barrier(0);

  for (int pp = 0; pp < (K >> 5); ++pp){
    const int p0 = pp * 2;
    const unsigned short* aB = smem + (size_t)(p0 & 6) * 8192;   // A-half p0
    const unsigned short* bB = aB + 8192;                        // B-half p0+1
    // ---- phase p0 (nh = 0) ----
    { int h = p0 + 5; if (h < nph) STAGE(h); }
    RDA(aB);
    RDB(bB, 0);
    asm volatile("s_barrier" ::: "memory");
    asm volatile("s_waitcnt lgkmcnt(0)" ::: "memory");
    __builtin_amdgcn_sched_barrier(0);
    __builtin_amdgcn_s_setprio(1);
    #pragma unroll
    for (int m = 0; m < 8; ++m){
      acc[m][0] = __builtin_amdgcn_mfma_f32_16x16x32_bf16(af[m], bfr[0], acc[m][0], 0, 0, 0);
      acc[m][1] = __builtin_amdgcn_mfma_f32_16x16x32_bf16(af[m], bfr[1], acc[m][1], 0, 0, 0);
    }
    __builtin_amdgcn_s_setprio(0);
    asm volatile("s_barrier" ::: "memory");
    __builtin_amdgcn_sched_barrier(0);
    // ---- phase p0+1 (nh = 1) ----
    { int h = p0 + 6; if (h < nph) STAGE(h); }
    RDB(bB, 1);
    asm volatile("s_barrier" ::: "memory");
    asm volatile("s_waitcnt lgkmcnt(0)" ::: "memory");
    __builtin_amdgcn_sched_barrier(0);
    __builtin_amdgcn_s_setprio(1);
    #pragma unroll
    for (int m = 0; m < 8; ++m){
      acc[m][2] = __builtin_amdgcn_mfma_f32_16x16x32_bf16(af[m], bfr[0], acc[m][2], 0, 0, 0);
      acc[m][3] = __builtin_amdgcn_mfma_f32_16x16x32_bf16(af[m], bfr[1], acc[m][3], 0, 0, 0);
    }
    __builtin_amdgcn_s_setprio(0);
    asm volatile("s_waitcnt vmcnt(6)\n\ts_barrier" ::: "memory");  // counted, never 0
    __builtin_amdgcn_sched_barrier(0);
  }

  #pragma unroll
  for (int m = 0; m < 8; ++m){
    int gr0 = rowBase + wr * 128 + m * 16 + lq * 4;
    #pragma unroll
    for (int n = 0; n < 4; ++n){
      int gc = colBase + wc * 64 + n * 16 + lr;
      #pragma unroll
      for (int q = 0; q < 4; ++q){
        float v = acc[m][n][q];
        if constexpr (ACT == 1) v = tanhf(v);
        else if constexpr (ACT == 2) v = v / (1.0f + __expf(-v));
        size_t off = (size_t)(gr0 + q) * N + gc;
        if constexpr (OUTBF16) ((unsigned short*)Cptr)[off] = f2bf(v);
        else                   ((float*)Cptr)[off] = v;
      }
    }
  }
}

// ------- einsum(4x K=32) via MFMA + lerp construction of xk/xv/xr/xg --------
__global__ __launch_bounds__(256) void mix_kernel(
    const float* __restrict__ xxx, const float* __restrict__ hidden,
    const float* __restrict__ attn_x, const float* __restrict__ w2,
    const float* __restrict__ tmk, const float* __restrict__ tmv,
    const float* __restrict__ tmr, const float* __restrict__ tmg,
    unsigned short* __restrict__ xk, unsigned short* __restrict__ xv,
    unsigned short* __restrict__ xr, unsigned short* __restrict__ xg)
{
  __shared__ __attribute__((aligned(16))) unsigned short smem[20992];
  unsigned short* xs   = smem;           // [64][168] bf16
  unsigned short* w2t  = smem + 10752;   // [4][64][40] bf16 (w2t[n][cc][j])
  unsigned short* out4 = smem;           // [4][64][72] bf16 (phase B overlay)

  const int tid = threadIdx.x;
  const int r0 = blockIdx.y * 64, c0 = blockIdx.x * 64;
  const int w = tid >> 6, lane = tid & 63, lr = lane & 15, lq = lane >> 4;

  for (int idx = tid; idx < 64 * 40; idx += 256){
    int r = idx / 40, cq = idx - r * 40;
    fvec4 v = *(const fvec4*)&xxx[(size_t)(r0 + r) * 160 + cq * 4];
    usvec4 o;
    o[0]=f2bf(v[0]); o[1]=f2bf(v[1]); o[2]=f2bf(v[2]); o[3]=f2bf(v[3]);
    *(usvec4*)&xs[r * 168 + cq * 4] = o;
  }
  for (int idx = tid; idx < 4 * 32 * 16; idx += 256){
    int n = idx >> 9;
    int rem = idx & 511;
    int j = rem >> 4, cq = rem & 15;
    fvec4 v = *(const fvec4*)&w2[(size_t)((n + 1) * 32 + j) * HID + c0 + cq * 4];
    #pragma unroll
    for (int cc = 0; cc < 4; ++cc)
      w2t[(n * 64 + cq * 4 + cc) * 40 + j] = f2bf(v[cc]);
  }
  __syncthreads();

  f32x4 acc[4][4] = {};
  #pragma unroll
  for (int n = 0; n < 4; ++n){
    bh8 afr = *reinterpret_cast<const bh8*>(&xs[(w * 16 + lr) * 168 + (n + 1) * 32 + lq * 8]);
    #pragma unroll
    for (int ct = 0; ct < 4; ++ct){
      bh8 bfr = *reinterpret_cast<const bh8*>(&w2t[(n * 64 + ct * 16 + lr) * 40 + lq * 8]);
      acc[ct][n] = __builtin_amdgcn_mfma_f32_16x16x32_bf16(afr, bfr, acc[ct][n], 0, 0, 0);
    }
  }
  __syncthreads();

  #pragma unroll
  for (int ct = 0; ct < 4; ++ct){
    int gc = c0 + ct * 16 + lr;
    float tk_ = tmk[gc], tv_ = tmv[gc], tr_ = tmr[gc], tg_ = tmg[gc];
    #pragma unroll
    for (int q = 0; q < 4; ++q){
      int row64 = w * 16 + lq * 4 + q;
      int gr = r0 + row64;
      size_t rowoff = (size_t)gr * HID + gc;
      float xx = hidden[rowoff];
      float pp = ((gr & (TSEQ - 1)) == 0) ? attn_x[(gr >> 11) * HID + gc]
                                          : hidden[rowoff - HID];
      float dxv = pp - xx;
      int lo = row64 * 72 + ct * 16 + lr;
      out4[(0 * 64 * 72) + lo] = f2bf(xx + dxv * (tk_ + acc[ct][0][q]));
      out4[(1 * 64 * 72) + lo] = f2bf(xx + dxv * (tv_ + acc[ct][1][q]));
      out4[(2 * 64 * 72) + lo] = f2bf(xx + dxv * (tr_ + acc[ct][2][q]));
      out4[(3 * 64 * 72) + lo] = f2bf(xx + dxv * (tg_ + acc[ct][3][q]));
    }
  }
  __syncthreads();

  #pragma unroll
  for (int a = 0; a < 4; ++a){
    unsigned short* dst = (a == 0) ? xk : (a == 1) ? xv : (a == 2) ? xr : xg;
    #pragma unroll
    for (int pass = 0; pass < 2; ++pass){
      int row64 = pass * 32 + (tid >> 3);
      int c8 = (tid & 7) * 8;
      usvec8 v8 = *(const usvec8*)&out4[(a * 64 + row64) * 72 + c8];
      *(usvec8*)&dst[(size_t)(r0 + row64) * HID + c0 + c8] = v8;
    }
  }
}

// --------- attention via MFMA: out0 = r@akv + rk*v ; group stats ------------
__global__ __launch_bounds__(256) void attn_kernel(
    const unsigned short* __restrict__ rb, const unsigned short* __restrict__ kb,
    const unsigned short* __restrict__ vb, const float* __restrict__ attn_kv,
    const float* __restrict__ faaaa, unsigned short* __restrict__ out0b,
    float* __restrict__ gsum, float* __restrict__ gsqs)
{
  const int bh = blockIdx.y;           // 128 = b*32+h
  const int b = bh >> 5, h = bh & 31;
  const int tid = threadIdx.x, lane = tid & 63, w = tid >> 6;
  const int lr = lane & 15, lq = lane >> 4;
  const int t0 = blockIdx.x * 256 + w * 64;
  const size_t rowbase = (size_t)(b * TSEQ + t0) * HID + h * 64;

  const float* akvp = attn_kv + (size_t)bh * 4096;
  bh8 bfr[2][4];
  #pragma unroll
  for (int kk = 0; kk < 2; ++kk)
    #pragma unroll
    for (int n = 0; n < 4; ++n)
      #pragma unroll
      for (int j = 0; j < 8; ++j)
        bfr[kk][n][j] = (__bf16)akvp[(kk * 32 + lq * 8 + j) * 64 + n * 16 + lr];

  float fa0[8], fa1[8];
  #pragma unroll
  for (int j = 0; j < 8; ++j){
    fa0[j] = faaaa[h * 64 + lq * 8 + j];
    fa1[j] = faaaa[h * 64 + 32 + lq * 8 + j];
  }

  __shared__ __attribute__((aligned(16))) float rk_s[4][64];
  __shared__ __attribute__((aligned(16))) unsigned short outb[4][64][72];

  f32x4 acc[4][4] = {};
  #pragma unroll
  for (int m = 0; m < 4; ++m){
    size_t ra = rowbase + (size_t)(m * 16 + lr) * HID;
    bh8 a0 = *reinterpret_cast<const bh8*>(&rb[ra + lq * 8]);
    bh8 a1 = *reinterpret_cast<const bh8*>(&rb[ra + 32 + lq * 8]);
    usvec8 k0 = *reinterpret_cast<const usvec8*>(&kb[ra + lq * 8]);
    usvec8 k1 = *reinterpret_cast<const usvec8*>(&kb[ra + 32 + lq * 8]);
    float p = 0.f;
    #pragma unroll
    for (int j = 0; j < 8; ++j){
      p += (float)a0[j] * fa0[j] * bf2f(k0[j]);
      p += (float)a1[j] * fa1[j] * bf2f(k1[j]);
    }
    p += __shfl_xor(p, 16, 64);
    p += __shfl_xor(p, 32, 64);
    if (lq == 0) rk_s[w][m * 16 + lr] = p;
    #pragma unroll
    for (int n = 0; n < 4; ++n){
      acc[m][n] = __builtin_amdgcn_mfma_f32_16x16x32_bf16(a0, bfr[0][n], acc[m][n], 0, 0, 0);
      acc[m][n] = __builtin_amdgcn_mfma_f32_16x16x32_bf16(a1, bfr[1][n], acc[m][n], 0, 0, 0);
    }
  }
  __syncthreads();

  float ssum = 0.f, ssq = 0.f;
  #pragma unroll
  for (int m = 0; m < 4; ++m){
    fvec4 rk4 = *(const fvec4*)&rk_s[w][m * 16 + lq * 4];
    #pragma unroll
    for (int n = 0; n < 4; ++n){
      int col = n * 16 + lr;
      #pragma unroll
      for (int q = 0; q < 4; ++q){
        int row = m * 16 + lq * 4 + q;
        float vv = bf2f(vb[rowbase + (size_t)row * HID + col]);
        float o = acc[m][n][q] + rk4[q] * vv;
        ssum += o; ssq += o * o;
        outb[w][row][col] = f2bf(o);
      }
    }
  }
  __syncthreads();
  #pragma unroll
  for (int pass = 0; pass < 8; ++pass){
    int row = pass * 8 + (lane >> 3);
    int c8 = (lane & 7) * 8;
    usvec8 o8 = *(const usvec8*)&outb[w][row][c8];
    *(usvec8*)&out0b[rowbase + (size_t)row * HID + c8] = o8;
  }
  #pragma unroll
  for (int off2 = 32; off2 > 0; off2 >>= 1){
    ssum += __shfl_xor(ssum, off2, 64);
    ssq  += __shfl_xor(ssq,  off2, 64);
  }
  if (lane == 0){ atomicAdd(&gsum[bh], ssum); atomicAdd(&gsqs[bh], ssq); }
}

__global__ void gn_stats_kernel(const float* __restrict__ gsum, const float* __restrict__ gsqs,
                                float* __restrict__ meaninv){
  int g = threadIdx.x;  // 128 groups
  const float n = (float)(TSEQ * 64);
  float mean = gsum[g] / n;
  float var = gsqs[g] / n - mean * mean;
  meaninv[2 * g]     = mean;
  meaninv[2 * g + 1] = rsqrtf(var + 1e-5f * 64.0f * 64.0f);
}

__global__ void ynorm_kernel(const unsigned short* __restrict__ out0b,
                             const unsigned short* __restrict__ gb,
                             const float* __restrict__ meaninv, const float* __restrict__ gamma,
                             const float* __restrict__ beta, unsigned short* __restrict__ yb){
  int i4 = blockIdx.x * 256 + threadIdx.x;
  int row = i4 >> 9, c4 = i4 & 511;
  int b = row >> 11;
  int c = c4 * 4;
  int g = b * 32 + (c >> 6);
  float mean = meaninv[2 * g], inv = meaninv[2 * g + 1];
  usvec4 o4 = *(const usvec4*)&out0b[(size_t)i4 * 4];
  usvec4 gv = *(const usvec4*)&gb[(size_t)i4 * 4];
  fvec4 ga = *(const fvec4*)&gamma[c];
  fvec4 be = *(const fvec4*)&beta[c];
  usvec4 y;
  #pragma unroll
  for (int cc = 0; cc < 4; ++cc){
    float val = ((bf2f(o4[cc]) - mean) * inv * ga[cc] + be[cc]) * bf2f(gv[cc]);
    y[cc] = f2bf(val);
  }
  *(usvec4*)&yb[(size_t)i4 * 4] = y;
}

// ---------------- exact f32 last-row path (w / k_last / v_last) -------------
__global__ void lastrow_mix_kernel(const float* __restrict__ xxx, const float* __restrict__ hidden,
    const float* __restrict__ w2, const float* __restrict__ tmw, const float* __restrict__ tmk,
    const float* __restrict__ tmv, float* __restrict__ xw_l, float* __restrict__ xk_l,
    float* __restrict__ xv_l){
  int b = blockIdx.y;
  int c = blockIdx.x * 256 + threadIdx.x;
  __shared__ float xsr[160];
  int i = b * TSEQ + (TSEQ - 1);
  if (threadIdx.x < 160) xsr[threadIdx.x] = xxx[(size_t)i * 160 + threadIdx.x];
  __syncthreads();
  float mw = 0.f, mk = 0.f, mv = 0.f;
  for (int j = 0; j < 32; ++j){
    mw += xsr[j]      * w2[(size_t)(j)      * HID + c];
    mk += xsr[32 + j] * w2[(size_t)(32 + j) * HID + c];
    mv += xsr[64 + j] * w2[(size_t)(64 + j) * HID + c];
  }
  float x = hidden[(size_t)i * HID + c];
  float prev = hidden[(size_t)(i - 1) * HID + c];
  float dx = prev - x;
  xw_l[b * HID + c] = x + dx * (tmw[c] + mw);
  xk_l[b * HID + c] = x + dx * (tmk[c] + mk);
  xv_l[b * HID + c] = x + dx * (tmv[c] + mv);
}

// ---- decay: hdec[b][j] = tanh(sum_c xw_l[b][c]*tdw1[c][j]) — split+reduce --
__global__ void decay1_part_kernel(const float* __restrict__ xw_l, const float* __restrict__ tdw1,
                                   float* __restrict__ dpart){
  int b = blockIdx.y;           // 4
  int chunk = blockIdx.x;       // 16 chunks of 128 c-rows
  int j = threadIdx.x & 63, sub = threadIdx.x >> 6;   // 4 subs x 32 rows
  float s = 0.f;
  int cbase = chunk * 128 + sub * 32;
  for (int r = 0; r < 32; ++r){
    int c = cbase + r;
    s += xw_l[b * HID + c] * tdw1[(size_t)c * 64 + j];
  }
  __shared__ float red[4][64];
  red[sub][j] = s;
  __syncthreads();
  if (sub == 0)
    dpart[((size_t)b * 16 + chunk) * 64 + j] = red[0][j] + red[1][j] + red[2][j] + red[3][j];
}

__global__ void decay1_reduce_kernel(const float* __restrict__ dpart, float* __restrict__ hdec){
  int tid = threadIdx.x;        // 256 = 4 b x 64 j
  int b = tid >> 6, j = tid & 63;
  float s = 0.f;
  #pragma unroll
  for (int chunk = 0; chunk < 16; ++chunk)
    s += dpart[((size_t)b * 16 + chunk) * 64 + j];
  hdec[b * 64 + j] = tanhf(s);
}

// ---- last-row k/v GEMVs: k-chunked partials (wide grid) + reduce -----------
__global__ __launch_bounds__(256) void lastrow_kv_part_kernel(
    const float* __restrict__ xk_l, const float* __restrict__ xv_l,
    const float* __restrict__ keyw, const float* __restrict__ valw,
    float* __restrict__ kpart, float* __restrict__ vpart){
  int c = blockIdx.x * 256 + threadIdx.x;   // 8 blocks -> 2048 cols
  int chunk = blockIdx.y;                   // 16 chunks of 128 rows
  __shared__ float xs[2][4][128];
  for (int i = threadIdx.x; i < 512; i += 256){
    int b = i >> 7, r = i & 127;
    xs[0][b][r] = xk_l[b * HID + chunk * 128 + r];
    xs[1][b][r] = xv_l[b * HID + chunk * 128 + r];
  }
  __syncthreads();
  float ka[4] = {0,0,0,0}, va[4] = {0,0,0,0};
  for (int r = 0; r < 128; ++r){
    int c2 = chunk * 128 + r;
    float kw = keyw[(size_t)c2 * HID + c];
    float vw = valw[(size_t)c2 * HID + c];
    #pragma unroll
    for (int b = 0; b < 4; ++b){
      ka[b] += xs[0][b][r] * kw;
      va[b] += xs[1][b][r] * vw;
    }
  }
  #pragma unroll
  for (int b = 0; b < 4; ++b){
    kpart[((size_t)chunk * 4 + b) * HID + c] = ka[b];
    vpart[((size_t)chunk * 4 + b) * HID + c] = va[b];
  }
}

__global__ void lastrow_kv_reduce_kernel(
    const float* __restrict__ kpart, const float* __restrict__ vpart,
    const float* __restrict__ hdec, const float* __restrict__ tdw2,
    const float* __restrict__ tdecay, float* __restrict__ klast,
    float* __restrict__ vlast, float* __restrict__ wlast){
  int c = blockIdx.x * 256 + threadIdx.x;   // 8 blocks -> 2048 cols
  float ka[4] = {0,0,0,0}, va[4] = {0,0,0,0};
  for (int chunk = 0; chunk < 16; ++chunk){
    #pragma unroll
    for (int b = 0; b < 4; ++b){
      ka[b] += kpart[((size_t)chunk * 4 + b) * HID + c];
      va[b] += vpart[((size_t)chunk * 4 + b) * HID + c];
    }
  }
  float tdc = tdecay[c];
  float td[4] = {tdc, tdc, tdc, tdc};
  for (int j = 0; j < 64; ++j){
    float w2v = tdw2[(size_t)j * HID + c];
    #pragma unroll
    for (int b = 0; b < 4; ++b) td[b] += hdec[b * 64 + j] * w2v;
  }
  #pragma unroll
  for (int b = 0; b < 4; ++b){
    klast[b * HID + c] = ka[b];
    vlast[b * HID + c] = va[b];
    wlast[b * HID + c] = expf(-expf(td[b]));
  }
}

__global__ void newkv_kernel(const float* __restrict__ klast, const float* __restrict__ vlast,
    const float* __restrict__ wlast, const float* __restrict__ attn_kv,
    float* __restrict__ outkv){
  int idx = blockIdx.x * 256 + threadIdx.x;  // < 524288
  int b = idx >> 17;
  int h = (idx >> 12) & 31;
  int d = (idx >> 6) & 63;
  int e = idx & 63;
  float kl = klast[b * HID + h * 64 + d];
  float vl = vlast[b * HID + h * 64 + e];
  float wl = wlast[b * HID + h * 64 + d];
  outkv[idx] = kl * vl + wl * attn_kv[idx];
}

__global__ void copies_kernel(const float* __restrict__ hidden, const float* __restrict__ ffnx,
                              float* __restrict__ out_attnx, float* __restrict__ out_ffnx){
  int i = blockIdx.x * 256 + threadIdx.x;
  if (i < BBATCH * HID){
    int b = i >> 11, c = i & 2047;
    out_attnx[i] = hidden[((size_t)(b * TSEQ + TSEQ - 1)) * HID + c];
    out_ffnx[i] = ffnx[i];
  }
}

// ---------------------------------------------------------------------------
extern "C" void kernel_launch(void* const* d_in, const int* in_sizes, int n_in,
                              void* d_out, int out_size, void* d_ws, size_t ws_size,
                              hipStream_t stream)
{
  (void)in_sizes; (void)n_in; (void)out_size;
  const float* hidden = (const float*)d_in[0];
  const float* attn_x = (const float*)d_in[1];
  const float* attn_kv = (const float*)d_in[2];
  const float* ffn_x = (const float*)d_in[3];
  const float* tmaa_x = (const float*)d_in[4];
  const float* tmaa_w = (const float*)d_in[5];
  const float* tmaa_k = (const float*)d_in[6];
  const float* tmaa_v = (const float*)d_in[7];
  const float* tmaa_r = (const float*)d_in[8];
  const float* tmaa_g = (const float*)d_in[9];
  const float* w1 = (const float*)d_in[10];
  const float* w2 = (const float*)d_in[11];
  const float* tdecay = (const float*)d_in[12];
  const float* tdw1 = (const float*)d_in[13];
  const float* tdw2 = (const float*)d_in[14];
  const float* faaaa = (const float*)d_in[15];
  const float* recw = (const float*)d_in[16];
  const float* keyw = (const float*)d_in[17];
  const float* valw = (const float*)d_in[18];
  const float* gatew = (const float*)d_in[19];
  const float* outw = (const float*)d_in[20];
  const float* gamma = (const float*)d_in[21];
  const float* beta = (const float*)d_in[22];

  // output segments (all f32): out | new_attn_x | new_attn_kv | ffn_x
  float* out_main  = (float*)d_out;
  float* out_attnx = out_main + (size_t)16777216;
  float* out_kv    = out_attnx + 8192;
  float* out_ffn   = out_kv + 524288;

  // Early scratch inside d_out (finalized only by the last GEMM):
  //  phase 1 (GEMMs): 4 transposed bf16 weights in [0,32MiB)
  //  phase 2 (attn..ynorm): bf16 out0 in [0,32MiB)
  unsigned short* wr_t = (unsigned short*)d_out;              // 2048x2048 bf16
  unsigned short* wk_t = wr_t + (size_t)4194304;
  unsigned short* wv_t = wk_t + (size_t)4194304;
  unsigned short* wg_t = wv_t + (size_t)4194304;              // ends at 32 MiB
  unsigned short* out0b = (unsigned short*)d_out;             // MROWS*HID bf16

  // workspace layout (~175 MiB), liveness-aliased big buffers:
  //   A: tm -> xg   B: xr -> kb -> yb   C: xk -> vb   D: xv -> gb   E: rb
  char* ws = (char*)d_ws;
  size_t off = 0;
  auto alloc = [&](size_t bytes) -> void* {
    void* p = ws + off; off += (bytes + 255) & ~(size_t)255; return p;
  };
  unsigned short* wo_t = (unsigned short*)alloc(2048ull * 2048 * 2);
  unsigned short* w1_t = (unsigned short*)alloc(160ull * 2048 * 2);
  float* xxx           = (float*)alloc((size_t)MROWS * 160 * 4);
  unsigned short* bufA = (unsigned short*)alloc((size_t)MROWS * HID * 2);
  unsigned short* bufB = (unsigned short*)alloc((size_t)MROWS * HID * 2);
  unsigned short* bufC = (unsigned short*)alloc((size_t)MROWS * HID * 2);
  unsigned short* bufD = (unsigned short*)alloc((size_t)MROWS * HID * 2);
  unsigned short* bufE = (unsigned short*)alloc((size_t)MROWS * HID * 2);
  float* gsum    = (float*)alloc(128 * 4);
  float* gsqs    = (float*)alloc(128 * 4);
  float* meaninv = (float*)alloc(256 * 4);
  float* xw_l  = (float*)alloc(BBATCH * HID * 4);
  float* xk_l  = (float*)alloc(BBATCH * HID * 4);
  float* xv_l  = (float*)alloc(BBATCH * HID * 4);
  float* klast = (float*)alloc(BBATCH * HID * 4);
  float* vlast = (float*)alloc(BBATCH * HID * 4);
  float* wlast = (float*)alloc(BBATCH * HID * 4);
  float* hdec  = (float*)alloc(BBATCH * 64 * 4);
  float* kpart = (float*)alloc(16ull * BBATCH * HID * 4);
  float* vpart = (float*)alloc(16ull * BBATCH * HID * 4);
  float* dpart = (float*)alloc((size_t)BBATCH * 16 * 64 * 4);

  if (off > ws_size) return;   // diagnostic: ws too small -> clean absmax fail

  unsigned short* tm = bufA;   // live: tmix .. w1-GEMM
  unsigned short* xg = bufA;   // live: mix .. g-GEMM
  unsigned short* xr = bufB;   // live: mix .. r-GEMM
  unsigned short* kb = bufB;   // live: k-GEMM .. attn
  unsigned short* yb = bufB;   // live: ynorm .. out-GEMM
  unsigned short* xk = bufC;   // live: mix .. k-GEMM
  unsigned short* vb = bufC;   // live: v-GEMM .. attn
  unsigned short* xv = bufD;   // live: mix .. v-GEMM
  unsigned short* gb = bufD;   // live: g-GEMM .. ynorm
  unsigned short* rb = bufE;   // live: r-GEMM .. attn

  dim3 tb(32, 8);
  tcast5_kernel<<<dim3(64, 64, 5), tb, 0, stream>>>(recw, keyw, valw, gatew, outw,
                                                    wr_t, wk_t, wv_t, wg_t, wo_t);
  tcast_kernel<<<dim3(5, 64),  tb, 0, stream>>>(w1,    w1_t, 2048, 160);
  zero_stats_kernel<<<1, 128, 0, stream>>>(gsum, gsqs);

  tmix_kernel<<<16384, 256, 0, stream>>>(hidden, attn_x, tmaa_x, tm);

  gemm_kernel<1, 0><<<dim3(2, 64), 256, 0, stream>>>(tm, w1_t, xxx, MROWS, 160, HID, 160);

  mix_kernel<<<dim3(32, 128), 256, 0, stream>>>(xxx, hidden, attn_x, w2,
      tmaa_k, tmaa_v, tmaa_r, tmaa_g, xk, xv, xr, xg);

  // big GEMMs: 256^2 tile, 8-phase schedule, grid 8x32 = 256 blocks (1/CU)
  gemm256_kernel<0, 1><<<dim3(8, 32), 512, 0, stream>>>(xr, wr_t, rb, HID);
  gemm256_kernel<0, 1><<<dim3(8, 32), 512, 0, stream>>>(xk, wk_t, kb, HID);
  gemm256_kernel<0, 1><<<dim3(8, 32), 512, 0, stream>>>(xv, wv_t, vb, HID);
  gemm256_kernel<2, 1><<<dim3(8, 32), 512, 0, stream>>>(xg, wg_t, gb, HID);

  // attn writes bf16 out0 over d_out[0,32MiB) (weight staging dead by now)
  attn_kernel<<<dim3(8, 128), 256, 0, stream>>>(rb, kb, vb, attn_kv, faaaa,
                                                out0b, gsum, gsqs);
  gn_stats_kernel<<<1, 128, 0, stream>>>(gsum, gsqs, meaninv);
  ynorm_kernel<<<16384, 256, 0, stream>>>(out0b, gb, meaninv, gamma, beta, yb);

  gemm256_kernel<0, 0><<<dim3(8, 32), 512, 0, stream>>>(yb, wo_t, out_main, HID);

  lastrow_mix_kernel<<<dim3(8, 4), 256, 0, stream>>>(xxx, hidden, w2, tmaa_w, tmaa_k, tmaa_v,
                                                     xw_l, xk_l, xv_l);
  decay1_part_kernel<<<dim3(16, 4), 256, 0, stream>>>(xw_l, tdw1, dpart);
  decay1_reduce_kernel<<<1, 256, 0, stream>>>(dpart, hdec);
  lastrow_kv_part_kernel<<<dim3(8, 16), 256, 0, stream>>>(xk_l, xv_l, keyw, valw, kpart, vpart);
  lastrow_kv_reduce_kernel<<<8, 256, 0, stream>>>(kpart, vpart, hdec, tdw2, tdecay,
                                                  klast, vlast, wlast);
  newkv_kernel<<<2048, 256, 0, stream>>>(klast, vlast, wlast, attn_kv, out_kv);
  copies_kernel<<<32, 256, 0, stream>>>(hidden, ffn_x, out_attnx, out_ffn);
}

// Round 10
// 676.990 us; speedup vs baseline: 1.0441x; 1.0197x over previous
//
#include <hip/hip_runtime.h>

#define HID 2048
#define TSEQ 2048
#define BBATCH 4
#define MROWS 8192   // B*T
#define NHEADS 32

typedef float fvec4 __attribute__((ext_vector_type(4)));
typedef unsigned short usvec4 __attribute__((ext_vector_type(4)));
typedef unsigned short usvec8 __attribute__((ext_vector_type(8)));
typedef __bf16 bh8 __attribute__((ext_vector_type(8)));
typedef float f32x4 __attribute__((ext_vector_type(4)));

__device__ __forceinline__ float bf2f(unsigned short u){
  return __uint_as_float(((unsigned int)u) << 16);
}
__device__ __forceinline__ unsigned short f2bf(float f){
  unsigned int u = __float_as_uint(f);
  return (unsigned short)((u + 0x7fffu + ((u >> 16) & 1u)) >> 16);
}
__device__ __forceinline__ void gll16(const void* g, void* lds){
  __builtin_amdgcn_global_load_lds(
      (const __attribute__((address_space(1))) unsigned int*)g,
      (__attribute__((address_space(3))) unsigned int*)lds, 16, 0, 0);
}

// pipeline sync: counted vmcnt + raw barrier in ONE asm (memory clobber blocks
// IR-level motion) + sched_barrier(0) (blocks MIR scheduler motion) — T4.
#define PIPE_SYNC(NSTR)                                              \
  asm volatile("s_waitcnt vmcnt(" NSTR ")\n\ts_barrier" ::: "memory"); \
  __builtin_amdgcn_sched_barrier(0);

// ---------------- transpose + cast f32 -> bf16 : out[c][r] = in[r][c] -------
__global__ void tcast_kernel(const float* __restrict__ in, unsigned short* __restrict__ out,
                             int R, int C){
  __shared__ float tile[32][33];
  int c0 = blockIdx.x * 32, r0 = blockIdx.y * 32;
  int tx = threadIdx.x, ty = threadIdx.y;
  for (int i = ty; i < 32; i += 8){
    int r = r0 + i, c = c0 + tx;
    tile[i][tx] = (r < R && c < C) ? in[(size_t)r * C + c] : 0.f;
  }
  __syncthreads();
  for (int i = ty; i < 32; i += 8){
    int c = c0 + i, r = r0 + tx;
    if (c < C && r < R) out[(size_t)c * R + r] = f2bf(tile[tx][i]);
  }
}

// 5 fixed 2048x2048 weight transposes in ONE dispatch (grid.z selects)
__global__ void tcast5_kernel(const float* __restrict__ i0, const float* __restrict__ i1,
                              const float* __restrict__ i2, const float* __restrict__ i3,
                              const float* __restrict__ i4,
                              unsigned short* __restrict__ o0, unsigned short* __restrict__ o1,
                              unsigned short* __restrict__ o2, unsigned short* __restrict__ o3,
                              unsigned short* __restrict__ o4){
  const float* in; unsigned short* out;
  switch (blockIdx.z){
    case 0:  in = i0; out = o0; break;
    case 1:  in = i1; out = o1; break;
    case 2:  in = i2; out = o2; break;
    case 3:  in = i3; out = o3; break;
    default: in = i4; out = o4; break;
  }
  __shared__ float tile[32][33];
  int c0 = blockIdx.x * 32, r0 = blockIdx.y * 32;
  int tx = threadIdx.x, ty = threadIdx.y;
  for (int i = ty; i < 32; i += 8)
    tile[i][tx] = in[(size_t)(r0 + i) * 2048 + c0 + tx];
  __syncthreads();
  for (int i = ty; i < 32; i += 8)
    out[(size_t)(c0 + i) * 2048 + r0 + tx] = f2bf(tile[tx][i]);
}

__global__ void zero_stats_kernel(float* __restrict__ gsum, float* __restrict__ gsqs){
  int i = threadIdx.x;  // 128 threads
  gsum[i] = 0.f;
  gsqs[i] = 0.f;
}

// ---------------- token-shift time_mix -> bf16 ------------------------------
__global__ void tmix_kernel(const float* __restrict__ hidden, const float* __restrict__ attn_x,
                            const float* __restrict__ tmx, unsigned short* __restrict__ tm){
  int i4 = blockIdx.x * 256 + threadIdx.x;        // over MROWS*HID/4
  int row = i4 >> 9;
  int c4 = i4 & 511;
  fvec4 x = *(const fvec4*)&hidden[(size_t)i4 * 4];
  fvec4 p;
  if ((row & (TSEQ - 1)) == 0){
    int b = row >> 11;
    p = *(const fvec4*)&attn_x[b * HID + c4 * 4];
  } else {
    p = *(const fvec4*)&hidden[(size_t)(i4 - 512) * 4];
  }
  fvec4 tx = *(const fvec4*)&tmx[c4 * 4];
  fvec4 t = x + (p - x) * tx;
  usvec4 o;
  o[0]=f2bf(t[0]); o[1]=f2bf(t[1]); o[2]=f2bf(t[2]); o[3]=f2bf(t[3]);
  *(usvec4*)&tm[(size_t)i4 * 4] = o;
}

// ---------------- m97-style bf16 GEMM (kept for the N=160 w1 GEMM) ----------
// ACT: 0 none, 1 tanh, 2 silu.  OUTBF16: store bf16 else f32.
template<int ACT, int OUTBF16>
__global__ __launch_bounds__(256, 2) void gemm_kernel(
    const unsigned short* __restrict__ A, const unsigned short* __restrict__ Bt,
    void* __restrict__ Cptr, int M, int N, int K, int ldc)
{
  __shared__ unsigned short As[128 * 32];
  __shared__ unsigned short Bs[128 * 32];
  const int tid = threadIdx.x;
  const int lane = tid & 63;
  const int w = tid >> 6;
  const int wr = w >> 1, wc = w & 1;
  const int lr = lane & 15, lq = lane >> 4;
  const int rowBase = blockIdx.y * 128;
  const int colBase = blockIdx.x * 128;

  const int arow = tid >> 2;
  const int ach = tid & 3;
  const unsigned short* aptr0 = A + (size_t)(rowBase + arow) * K + ach * 8;
  const unsigned short* aptr1 = aptr0 + (size_t)64 * K;
  int br0 = colBase + arow;      if (br0 > N - 1) br0 = N - 1;
  int br1 = colBase + arow + 64; if (br1 > N - 1) br1 = N - 1;
  const unsigned short* bptr0 = Bt + (size_t)br0 * K + ach * 8;
  const unsigned short* bptr1 = Bt + (size_t)br1 * K + ach * 8;

  f32x4 acc[4][4] = {};

  const int nk = K >> 5;
  for (int kk = 0; kk < nk; ++kk){
    gll16(aptr0, &As[tid * 8]);
    gll16(aptr1, &As[(tid + 256) * 8]);
    gll16(bptr0, &Bs[tid * 8]);
    gll16(bptr1, &Bs[(tid + 256) * 8]);
    aptr0 += 32; aptr1 += 32; bptr0 += 32; bptr1 += 32;
    __syncthreads();
    bh8 af[4], bfv[4];
    #pragma unroll
    for (int m = 0; m < 4; ++m)
      af[m] = *reinterpret_cast<const bh8*>(&As[(wr * 64 + m * 16 + lr) * 32 + lq * 8]);
    #pragma unroll
    for (int n = 0; n < 4; ++n)
      bfv[n] = *reinterpret_cast<const bh8*>(&Bs[(wc * 64 + n * 16 + lr) * 32 + lq * 8]);
    #pragma unroll
    for (int m = 0; m < 4; ++m)
      #pragma unroll
      for (int n = 0; n < 4; ++n)
        acc[m][n] = __builtin_amdgcn_mfma_f32_16x16x32_bf16(af[m], bfv[n], acc[m][n], 0, 0, 0);
    __syncthreads();
  }

  #pragma unroll
  for (int m = 0; m < 4; ++m){
    int gr0 = rowBase + wr * 64 + m * 16 + lq * 4;
    #pragma unroll
    for (int n = 0; n < 4; ++n){
      int gc = colBase + wc * 64 + n * 16 + lr;
      if (gc < N){
        #pragma unroll
        for (int q = 0; q < 4; ++q){
          float v = acc[m][n][q];
          if constexpr (ACT == 1) v = tanhf(v);
          else if constexpr (ACT == 2) v = v / (1.0f + __expf(-v));
          size_t off = (size_t)(gr0 + q) * ldc + gc;
          if constexpr (OUTBF16) ((unsigned short*)Cptr)[off] = f2bf(v);
          else                   ((float*)Cptr)[off] = v;
        }
      }
    }
  }
}

// -- 256x256 bf16 GEMM, BK=32, 4-buffer LDS, counted-vmcnt pipeline (T3+T4) --
// C = A(MxK) * Bt(NxK)^T.  M,N multiples of 256, K multiple of 32 (>=128).
// Swizzle: LDS[r][c] holds global chunk c ^ ((r>>1)&3); read-side per-lane
// constant ksel. XCD-aware block remap (T1). act runtime: 0 none, 2 silu.
template<int OUTBF16>
__device__ __forceinline__ void gemm256_body(
    const unsigned short* __restrict__ A, const unsigned short* __restrict__ Bt,
    void* __restrict__ Cptr, int K, int act)
{
  __shared__ unsigned short smem[65536];   // 4 buf x (A 8192 + B 8192) elems
  const int tid = threadIdx.x;
  const int lane = tid & 63, w = tid >> 6;
  const int wr = w >> 2, wc = w & 3;           // 2M x 4N waves
  const int lr = lane & 15, lq = lane >> 4;

  // T1: XCD-aware bijective remap (grid 8x32 = 256 blocks = 1/CU per slice)
  const int bid = blockIdx.y * gridDim.x + blockIdx.x;
  const int xcd = bid & 7, qq = bid >> 3;
  const int by = xcd * 4 + (qq >> 3);          // 0..31
  const int bx = qq & 7;                       // 0..7
  const int rowBase = by * 256;
  const int colBase = bx * 256;
  const int N = gridDim.x * 256;               // = ldc

  // staging descriptors: 2 gll A + 2 gll B per K-tile per thread
  const unsigned short* srcA[2]; const unsigned short* srcB[2];
  int dstA[2], dstB[2];
  #pragma unroll
  for (int l = 0; l < 2; ++l){
    int ci = l * 512 + tid;          // 0..1023
    int r = ci >> 2, c = ci & 3;     // row 0..255, chunk 0..3 (8 elems each)
    int g = c ^ ((r >> 1) & 3);      // pre-swizzled global chunk
    srcA[l] = A  + (size_t)(rowBase + r) * K + g * 8;
    srcB[l] = Bt + (size_t)(colBase + r) * K + g * 8;
    dstA[l] = ci * 8;
    dstB[l] = 8192 + ci * 8;
  }

  f32x4 acc[8][4] = {};
  const int ksel = (lq ^ ((lr >> 1) & 3)) * 8;   // per-lane swizzled k-chunk

  auto STAGE = [&](int t, int bi){
    unsigned short* buf = smem + bi * 16384;
    #pragma unroll
    for (int l = 0; l < 2; ++l){
      gll16(srcA[l] + (size_t)t * 32, buf + dstA[l]);
      gll16(srcB[l] + (size_t)t * 32, buf + dstB[l]);
    }
  };

  auto COMPUTE = [&](int bi){
    const unsigned short* aB = smem + bi * 16384;
    const unsigned short* bB = aB + 8192;
    bh8 af[8], bf[4];
    #pragma unroll
    for (int m = 0; m < 8; ++m)
      af[m] = *reinterpret_cast<const bh8*>(&aB[(wr * 128 + m * 16 + lr) * 32 + ksel]);
    #pragma unroll
    for (int n = 0; n < 4; ++n)
      bf[n] = *reinterpret_cast<const bh8*>(&bB[(wc * 64 + n * 16 + lr) * 32 + ksel]);
    __builtin_amdgcn_s_setprio(1);
    #pragma unroll
    for (int m = 0; m < 8; ++m)
      #pragma unroll
      for (int n = 0; n < 4; ++n)
        acc[m][n] = __builtin_amdgcn_mfma_f32_16x16x32_bf16(af[m], bf[n], acc[m][n], 0, 0, 0);
    __builtin_amdgcn_s_setprio(0);
  };

  const int nt = K >> 5;   // >= 4
  // prologue: prefetch tiles 0..2 (12 gll in flight; wait oldest 4 = tile 0)
  STAGE(0, 0); STAGE(1, 1); STAGE(2, 2);
  PIPE_SYNC("8");
  // steady state: stage t+3, compute t, wait tile t+1's loads (vmcnt 12->8)
  for (int t = 0; t < nt - 3; ++t){
    STAGE(t + 3, (t + 3) & 3);
    COMPUTE(t & 3);
    PIPE_SYNC("8");
  }
  COMPUTE((nt - 3) & 3);
  PIPE_SYNC("4");
  COMPUTE((nt - 2) & 3);
  PIPE_SYNC("0");
  COMPUTE((nt - 1) & 3);

  #pragma unroll
  for (int m = 0; m < 8; ++m){
    int gr0 = rowBase + wr * 128 + m * 16 + lq * 4;
    #pragma unroll
    for (int n = 0; n < 4; ++n){
      int gc = colBase + wc * 64 + n * 16 + lr;
      #pragma unroll
      for (int q = 0; q < 4; ++q){
        float v = acc[m][n][q];
        if (act == 2) v = v / (1.0f + __expf(-v));
        size_t off = (size_t)(gr0 + q) * N + gc;
        if constexpr (OUTBF16) ((unsigned short*)Cptr)[off] = f2bf(v);
        else                   ((float*)Cptr)[off] = v;
      }
    }
  }
}

// fused r/k/v/g projections: grid (8,32,4); z=3 applies silu
__global__ __launch_bounds__(512, 2) void gemm256x4_kernel(
    const unsigned short* __restrict__ A0, const unsigned short* __restrict__ A1,
    const unsigned short* __restrict__ A2, const unsigned short* __restrict__ A3,
    const unsigned short* __restrict__ B0, const unsigned short* __restrict__ B1,
    const unsigned short* __restrict__ B2, const unsigned short* __restrict__ B3,
    unsigned short* __restrict__ C0, unsigned short* __restrict__ C1,
    unsigned short* __restrict__ C2, unsigned short* __restrict__ C3, int K)
{
  const unsigned short* A; const unsigned short* Bt; unsigned short* C; int act = 0;
  switch (blockIdx.z){
    case 0:  A = A0; Bt = B0; C = C0; break;
    case 1:  A = A1; Bt = B1; C = C1; break;
    case 2:  A = A2; Bt = B2; C = C2; break;
    default: A = A3; Bt = B3; C = C3; act = 2; break;
  }
  gemm256_body<1>(A, Bt, C, K, act);
}

__global__ __launch_bounds__(512, 2) void gemm256f_kernel(
    const unsigned short* __restrict__ A, const unsigned short* __restrict__ Bt,
    float* __restrict__ C, int K)
{
  gemm256_body<0>(A, Bt, C, K, 0);
}

// ------- einsum(4x K=32) via MFMA + lerp construction of xk/xv/xr/xg --------
__global__ __launch_bounds__(256) void mix_kernel(
    const float* __restrict__ xxx, const float* __restrict__ hidden,
    const float* __restrict__ attn_x, const float* __restrict__ w2,
    const float* __restrict__ tmk, const float* __restrict__ tmv,
    const float* __restrict__ tmr, const float* __restrict__ tmg,
    unsigned short* __restrict__ xk, unsigned short* __restrict__ xv,
    unsigned short* __restrict__ xr, unsigned short* __restrict__ xg)
{
  __shared__ __attribute__((aligned(16))) unsigned short smem[20992];
  unsigned short* xs   = smem;           // [64][168] bf16
  unsigned short* w2t  = smem + 10752;   // [4][64][40] bf16 (w2t[n][cc][j])
  unsigned short* out4 = smem;           // [4][64][72] bf16 (phase B overlay)

  const int tid = threadIdx.x;
  const int r0 = blockIdx.y * 64, c0 = blockIdx.x * 64;
  const int w = tid >> 6, lane = tid & 63, lr = lane & 15, lq = lane >> 4;

  for (int idx = tid; idx < 64 * 40; idx += 256){
    int r = idx / 40, cq = idx - r * 40;
    fvec4 v = *(const fvec4*)&xxx[(size_t)(r0 + r) * 160 + cq * 4];
    usvec4 o;
    o[0]=f2bf(v[0]); o[1]=f2bf(v[1]); o[2]=f2bf(v[2]); o[3]=f2bf(v[3]);
    *(usvec4*)&xs[r * 168 + cq * 4] = o;
  }
  for (int idx = tid; idx < 4 * 32 * 16; idx += 256){
    int n = idx >> 9;
    int rem = idx & 511;
    int j = rem >> 4, cq = rem & 15;
    fvec4 v = *(const fvec4*)&w2[(size_t)((n + 1) * 32 + j) * HID + c0 + cq * 4];
    #pragma unroll
    for (int cc = 0; cc < 4; ++cc)
      w2t[(n * 64 + cq * 4 + cc) * 40 + j] = f2bf(v[cc]);
  }
  __syncthreads();

  f32x4 acc[4][4] = {};
  #pragma unroll
  for (int n = 0; n < 4; ++n){
    bh8 afr = *reinterpret_cast<const bh8*>(&xs[(w * 16 + lr) * 168 + (n + 1) * 32 + lq * 8]);
    #pragma unroll
    for (int ct = 0; ct < 4; ++ct){
      bh8 bfr = *reinterpret_cast<const bh8*>(&w2t[(n * 64 + ct * 16 + lr) * 40 + lq * 8]);
      acc[ct][n] = __builtin_amdgcn_mfma_f32_16x16x32_bf16(afr, bfr, acc[ct][n], 0, 0, 0);
    }
  }
  __syncthreads();

  #pragma unroll
  for (int ct = 0; ct < 4; ++ct){
    int gc = c0 + ct * 16 + lr;
    float tk_ = tmk[gc], tv_ = tmv[gc], tr_ = tmr[gc], tg_ = tmg[gc];
    #pragma unroll
    for (int q = 0; q < 4; ++q){
      int row64 = w * 16 + lq * 4 + q;
      int gr = r0 + row64;
      size_t rowoff = (size_t)gr * HID + gc;
      float xx = hidden[rowoff];
      float pp = ((gr & (TSEQ - 1)) == 0) ? attn_x[(gr >> 11) * HID + gc]
                                          : hidden[rowoff - HID];
      float dxv = pp - xx;
      int lo = row64 * 72 + ct * 16 + lr;
      out4[(0 * 64 * 72) + lo] = f2bf(xx + dxv * (tk_ + acc[ct][0][q]));
      out4[(1 * 64 * 72) + lo] = f2bf(xx + dxv * (tv_ + acc[ct][1][q]));
      out4[(2 * 64 * 72) + lo] = f2bf(xx + dxv * (tr_ + acc[ct][2][q]));
      out4[(3 * 64 * 72) + lo] = f2bf(xx + dxv * (tg_ + acc[ct][3][q]));
    }
  }
  __syncthreads();

  #pragma unroll
  for (int a = 0; a < 4; ++a){
    unsigned short* dst = (a == 0) ? xk : (a == 1) ? xv : (a == 2) ? xr : xg;
    #pragma unroll
    for (int pass = 0; pass < 2; ++pass){
      int row64 = pass * 32 + (tid >> 3);
      int c8 = (tid & 7) * 8;
      usvec8 v8 = *(const usvec8*)&out4[(a * 64 + row64) * 72 + c8];
      *(usvec8*)&dst[(size_t)(r0 + row64) * HID + c0 + c8] = v8;
    }
  }
}

// --------- attention via MFMA: out0 = r@akv + rk*v ; group stats ------------
__global__ __launch_bounds__(256) void attn_kernel(
    const unsigned short* __restrict__ rb, const unsigned short* __restrict__ kb,
    const unsigned short* __restrict__ vb, const float* __restrict__ attn_kv,
    const float* __restrict__ faaaa, unsigned short* __restrict__ out0b,
    float* __restrict__ gsum, float* __restrict__ gsqs)
{
  const int bh = blockIdx.y;           // 128 = b*32+h
  const int b = bh >> 5, h = bh & 31;
  const int tid = threadIdx.x, lane = tid & 63, w = tid >> 6;
  const int lr = lane & 15, lq = lane >> 4;
  const int t0 = blockIdx.x * 256 + w * 64;
  const size_t rowbase = (size_t)(b * TSEQ + t0) * HID + h * 64;

  const float* akvp = attn_kv + (size_t)bh * 4096;
  bh8 bfr[2][4];
  #pragma unroll
  for (int kk = 0; kk < 2; ++kk)
    #pragma unroll
    for (int n = 0; n < 4; ++n)
      #pragma unroll
      for (int j = 0; j < 8; ++j)
        bfr[kk][n][j] = (__bf16)akvp[(kk * 32 + lq * 8 + j) * 64 + n * 16 + lr];

  float fa0[8], fa1[8];
  #pragma unroll
  for (int j = 0; j < 8; ++j){
    fa0[j] = faaaa[h * 64 + lq * 8 + j];
    fa1[j] = faaaa[h * 64 + 32 + lq * 8 + j];
  }

  __shared__ __attribute__((aligned(16))) float rk_s[4][64];
  __shared__ __attribute__((aligned(16))) unsigned short outb[4][64][72];

  f32x4 acc[4][4] = {};
  #pragma unroll
  for (int m = 0; m < 4; ++m){
    size_t ra = rowbase + (size_t)(m * 16 + lr) * HID;
    bh8 a0 = *reinterpret_cast<const bh8*>(&rb[ra + lq * 8]);
    bh8 a1 = *reinterpret_cast<const bh8*>(&rb[ra + 32 + lq * 8]);
    usvec8 k0 = *reinterpret_cast<const usvec8*>(&kb[ra + lq * 8]);
    usvec8 k1 = *reinterpret_cast<const usvec8*>(&kb[ra + 32 + lq * 8]);
    float p = 0.f;
    #pragma unroll
    for (int j = 0; j < 8; ++j){
      p += (float)a0[j] * fa0[j] * bf2f(k0[j]);
      p += (float)a1[j] * fa1[j] * bf2f(k1[j]);
    }
    p += __shfl_xor(p, 16, 64);
    p += __shfl_xor(p, 32, 64);
    if (lq == 0) rk_s[w][m * 16 + lr] = p;
    #pragma unroll
    for (int n = 0; n < 4; ++n){
      acc[m][n] = __builtin_amdgcn_mfma_f32_16x16x32_bf16(a0, bfr[0][n], acc[m][n], 0, 0, 0);
      acc[m][n] = __builtin_amdgcn_mfma_f32_16x16x32_bf16(a1, bfr[1][n], acc[m][n], 0, 0, 0);
    }
  }
  __syncthreads();

  float ssum = 0.f, ssq = 0.f;
  #pragma unroll
  for (int m = 0; m < 4; ++m){
    fvec4 rk4 = *(const fvec4*)&rk_s[w][m * 16 + lq * 4];
    #pragma unroll
    for (int n = 0; n < 4; ++n){
      int col = n * 16 + lr;
      #pragma unroll
      for (int q = 0; q < 4; ++q){
        int row = m * 16 + lq * 4 + q;
        float vv = bf2f(vb[rowbase + (size_t)row * HID + col]);
        float o = acc[m][n][q] + rk4[q] * vv;
        ssum += o; ssq += o * o;
        outb[w][row][col] = f2bf(o);
      }
    }
  }
  __syncthreads();
  #pragma unroll
  for (int pass = 0; pass < 8; ++pass){
    int row = pass * 8 + (lane >> 3);
    int c8 = (lane & 7) * 8;
    usvec8 o8 = *(const usvec8*)&outb[w][row][c8];
    *(usvec8*)&out0b[rowbase + (size_t)row * HID + c8] = o8;
  }
  #pragma unroll
  for (int off2 = 32; off2 > 0; off2 >>= 1){
    ssum += __shfl_xor(ssum, off2, 64);
    ssq  += __shfl_xor(ssq,  off2, 64);
  }
  if (lane == 0){ atomicAdd(&gsum[bh], ssum); atomicAdd(&gsqs[bh], ssq); }
}

// ynorm with inlined group stats (gn_stats folded in)
__global__ void ynorm_kernel(const unsigned short* __restrict__ out0b,
                             const unsigned short* __restrict__ gb,
                             const float* __restrict__ gsum, const float* __restrict__ gsqs,
                             const float* __restrict__ gamma,
                             const float* __restrict__ beta, unsigned short* __restrict__ yb){
  int i4 = blockIdx.x * 256 + threadIdx.x;
  int row = i4 >> 9, c4 = i4 & 511;
  int b = row >> 11;
  int c = c4 * 4;
  int g = b * 32 + (c >> 6);
  const float rn = 1.0f / (float)(TSEQ * 64);
  float mean = gsum[g] * rn;
  float var  = gsqs[g] * rn - mean * mean;
  float inv  = rsqrtf(var + 1e-5f * 64.0f * 64.0f);
  usvec4 o4 = *(const usvec4*)&out0b[(size_t)i4 * 4];
  usvec4 gv = *(const usvec4*)&gb[(size_t)i4 * 4];
  fvec4 ga = *(const fvec4*)&gamma[c];
  fvec4 be = *(const fvec4*)&beta[c];
  usvec4 y;
  #pragma unroll
  for (int cc = 0; cc < 4; ++cc){
    float val = ((bf2f(o4[cc]) - mean) * inv * ga[cc] + be[cc]) * bf2f(gv[cc]);
    y[cc] = f2bf(val);
  }
  *(usvec4*)&yb[(size_t)i4 * 4] = y;
}

// ---------------- exact f32 last-row path (w / k_last / v_last) -------------
__global__ void lastrow_mix_kernel(const float* __restrict__ xxx, const float* __restrict__ hidden,
    const float* __restrict__ w2, const float* __restrict__ tmw, const float* __restrict__ tmk,
    const float* __restrict__ tmv, float* __restrict__ xw_l, float* __restrict__ xk_l,
    float* __restrict__ xv_l){
  int b = blockIdx.y;
  int c = blockIdx.x * 256 + threadIdx.x;
  __shared__ float xsr[160];
  int i = b * TSEQ + (TSEQ - 1);
  if (threadIdx.x < 160) xsr[threadIdx.x] = xxx[(size_t)i * 160 + threadIdx.x];
  __syncthreads();
  float mw = 0.f, mk = 0.f, mv = 0.f;
  for (int j = 0; j < 32; ++j){
    mw += xsr[j]      * w2[(size_t)(j)      * HID + c];
    mk += xsr[32 + j] * w2[(size_t)(32 + j) * HID + c];
    mv += xsr[64 + j] * w2[(size_t)(64 + j) * HID + c];
  }
  float x = hidden[(size_t)i * HID + c];
  float prev = hidden[(size_t)(i - 1) * HID + c];
  float dx = prev - x;
  xw_l[b * HID + c] = x + dx * (tmw[c] + mw);
  xk_l[b * HID + c] = x + dx * (tmk[c] + mk);
  xv_l[b * HID + c] = x + dx * (tmv[c] + mv);
}

// ---- decay: hdec[b][j] = tanh(sum_c xw_l[b][c]*tdw1[c][j]) — split+reduce --
__global__ void decay1_part_kernel(const float* __restrict__ xw_l, const float* __restrict__ tdw1,
                                   float* __restrict__ dpart){
  int b = blockIdx.y;           // 4
  int chunk = blockIdx.x;       // 16 chunks of 128 c-rows
  int j = threadIdx.x & 63, sub = threadIdx.x >> 6;   // 4 subs x 32 rows
  float s = 0.f;
  int cbase = chunk * 128 + sub * 32;
  for (int r = 0; r < 32; ++r){
    int c = cbase + r;
    s += xw_l[b * HID + c] * tdw1[(size_t)c * 64 + j];
  }
  __shared__ float red[4][64];
  red[sub][j] = s;
  __syncthreads();
  if (sub == 0)
    dpart[((size_t)b * 16 + chunk) * 64 + j] = red[0][j] + red[1][j] + red[2][j] + red[3][j];
}

__global__ void decay1_reduce_kernel(const float* __restrict__ dpart, float* __restrict__ hdec){
  int tid = threadIdx.x;        // 256 = 4 b x 64 j
  int b = tid >> 6, j = tid & 63;
  float s = 0.f;
  #pragma unroll
  for (int chunk = 0; chunk < 16; ++chunk)
    s += dpart[((size_t)b * 16 + chunk) * 64 + j];
  hdec[b * 64 + j] = tanhf(s);
}

// ---- last-row k/v GEMVs: k-chunked partials (wide grid) + reduce -----------
__global__ __launch_bounds__(256) void lastrow_kv_part_kernel(
    const float* __restrict__ xk_l, const float* __restrict__ xv_l,
    const float* __restrict__ keyw, const float* __restrict__ valw,
    float* __restrict__ kpart, float* __restrict__ vpart){
  int c = blockIdx.x * 256 + threadIdx.x;   // 8 blocks -> 2048 cols
  int chunk = blockIdx.y;                   // 16 chunks of 128 rows
  __shared__ float xs[2][4][128];
  for (int i = threadIdx.x; i < 512; i += 256){
    int b = i >> 7, r = i & 127;
    xs[0][b][r] = xk_l[b * HID + chunk * 128 + r];
    xs[1][b][r] = xv_l[b * HID + chunk * 128 + r];
  }
  __syncthreads();
  float ka[4] = {0,0,0,0}, va[4] = {0,0,0,0};
  for (int r = 0; r < 128; ++r){
    int c2 = chunk * 128 + r;
    float kw = keyw[(size_t)c2 * HID + c];
    float vw = valw[(size_t)c2 * HID + c];
    #pragma unroll
    for (int b = 0; b < 4; ++b){
      ka[b] += xs[0][b][r] * kw;
      va[b] += xs[1][b][r] * vw;
    }
  }
  #pragma unroll
  for (int b = 0; b < 4; ++b){
    kpart[((size_t)chunk * 4 + b) * HID + c] = ka[b];
    vpart[((size_t)chunk * 4 + b) * HID + c] = va[b];
  }
}

__global__ void lastrow_kv_reduce_kernel(
    const float* __restrict__ kpart, const float* __restrict__ vpart,
    const float* __restrict__ hdec, const float* __restrict__ tdw2,
    const float* __restrict__ tdecay, float* __restrict__ klast,
    float* __restrict__ vlast, float* __restrict__ wlast){
  int c = blockIdx.x * 256 + threadIdx.x;   // 8 blocks -> 2048 cols
  float ka[4] = {0,0,0,0}, va[4] = {0,0,0,0};
  for (int chunk = 0; chunk < 16; ++chunk){
    #pragma unroll
    for (int b = 0; b < 4; ++b){
      ka[b] += kpart[((size_t)chunk * 4 + b) * HID + c];
      va[b] += vpart[((size_t)chunk * 4 + b) * HID + c];
    }
  }
  float tdc = tdecay[c];
  float td[4] = {tdc, tdc, tdc, tdc};
  for (int j = 0; j < 64; ++j){
    float w2v = tdw2[(size_t)j * HID + c];
    #pragma unroll
    for (int b = 0; b < 4; ++b) td[b] += hdec[b * 64 + j] * w2v;
  }
  #pragma unroll
  for (int b = 0; b < 4; ++b){
    klast[b * HID + c] = ka[b];
    vlast[b * HID + c] = va[b];
    wlast[b * HID + c] = expf(-expf(td[b]));
  }
}

__global__ void newkv_kernel(const float* __restrict__ klast, const float* __restrict__ vlast,
    const float* __restrict__ wlast, const float* __restrict__ attn_kv,
    float* __restrict__ outkv){
  int idx = blockIdx.x * 256 + threadIdx.x;  // < 524288
  int b = idx >> 17;
  int h = (idx >> 12) & 31;
  int d = (idx >> 6) & 63;
  int e = idx & 63;
  float kl = klast[b * HID + h * 64 + d];
  float vl = vlast[b * HID + h * 64 + e];
  float wl = wlast[b * HID + h * 64 + d];
  outkv[idx] = kl * vl + wl * attn_kv[idx];
}

__global__ void copies_kernel(const float* __restrict__ hidden, const float* __restrict__ ffnx,
                              float* __restrict__ out_attnx, float* __restrict__ out_ffnx){
  int i = blockIdx.x * 256 + threadIdx.x;
  if (i < BBATCH * HID){
    int b = i >> 11, c = i & 2047;
    out_attnx[i] = hidden[((size_t)(b * TSEQ + TSEQ - 1)) * HID + c];
    out_ffnx[i] = ffnx[i];
  }
}

// ---------------------------------------------------------------------------
extern "C" void kernel_launch(void* const* d_in, const int* in_sizes, int n_in,
                              void* d_out, int out_size, void* d_ws, size_t ws_size,
                              hipStream_t stream)
{
  (void)in_sizes; (void)n_in; (void)out_size;
  const float* hidden = (const float*)d_in[0];
  const float* attn_x = (const float*)d_in[1];
  const float* attn_kv = (const float*)d_in[2];
  const float* ffn_x = (const float*)d_in[3];
  const float* tmaa_x = (const float*)d_in[4];
  const float* tmaa_w = (const float*)d_in[5];
  const float* tmaa_k = (const float*)d_in[6];
  const float* tmaa_v = (const float*)d_in[7];
  const float* tmaa_r = (const float*)d_in[8];
  const float* tmaa_g = (const float*)d_in[9];
  const float* w1 = (const float*)d_in[10];
  const float* w2 = (const float*)d_in[11];
  const float* tdecay = (const float*)d_in[12];
  const float* tdw1 = (const float*)d_in[13];
  const float* tdw2 = (const float*)d_in[14];
  const float* faaaa = (const float*)d_in[15];
  const float* recw = (const float*)d_in[16];
  const float* keyw = (const float*)d_in[17];
  const float* valw = (const float*)d_in[18];
  const float* gatew = (const float*)d_in[19];
  const float* outw = (const float*)d_in[20];
  const float* gamma = (const float*)d_in[21];
  const float* beta = (const float*)d_in[22];

  // output segments (all f32): out | new_attn_x | new_attn_kv | ffn_x
  float* out_main  = (float*)d_out;
  float* out_attnx = out_main + (size_t)16777216;
  float* out_kv    = out_attnx + 8192;
  float* out_ffn   = out_kv + 524288;

  // Early scratch inside d_out (finalized only by the last GEMM):
  //  phase 1 (GEMMs): 4 transposed bf16 weights in [0,32MiB)
  //  phase 2 (attn..ynorm): bf16 out0 in [0,32MiB)
  unsigned short* wr_t = (unsigned short*)d_out;              // 2048x2048 bf16
  unsigned short* wk_t = wr_t + (size_t)4194304;
  unsigned short* wv_t = wk_t + (size_t)4194304;
  unsigned short* wg_t = wv_t + (size_t)4194304;              // ends at 32 MiB
  unsigned short* out0b = (unsigned short*)d_out;             // MROWS*HID bf16

  // workspace layout (~175 MiB), liveness-aliased big buffers:
  //   A: tm -> xg   B: xr -> kb -> yb   C: xk -> vb   D: xv -> gb   E: rb
  char* ws = (char*)d_ws;
  size_t off = 0;
  auto alloc = [&](size_t bytes) -> void* {
    void* p = ws + off; off += (bytes + 255) & ~(size_t)255; return p;
  };
  unsigned short* wo_t = (unsigned short*)alloc(2048ull * 2048 * 2);
  unsigned short* w1_t = (unsigned short*)alloc(160ull * 2048 * 2);
  float* xxx           = (float*)alloc((size_t)MROWS * 160 * 4);
  unsigned short* bufA = (unsigned short*)alloc((size_t)MROWS * HID * 2);
  unsigned short* bufB = (unsigned short*)alloc((size_t)MROWS * HID * 2);
  unsigned short* bufC = (unsigned short*)alloc((size_t)MROWS * HID * 2);
  unsigned short* bufD = (unsigned short*)alloc((size_t)MROWS * HID * 2);
  unsigned short* bufE = (unsigned short*)alloc((size_t)MROWS * HID * 2);
  float* gsum    = (float*)alloc(128 * 4);
  float* gsqs    = (float*)alloc(128 * 4);
  float* meaninv = (float*)alloc(256 * 4);
  float* xw_l  = (float*)alloc(BBATCH * HID * 4);
  float* xk_l  = (float*)alloc(BBATCH * HID * 4);
  float* xv_l  = (float*)alloc(BBATCH * HID * 4);
  float* klast = (float*)alloc(BBATCH * HID * 4);
  float* vlast = (float*)alloc(BBATCH * HID * 4);
  float* wlast = (float*)alloc(BBATCH * HID * 4);
  float* hdec  = (float*)alloc(BBATCH * 64 * 4);
  float* kpart = (float*)alloc(16ull * BBATCH * HID * 4);
  float* vpart = (float*)alloc(16ull * BBATCH * HID * 4);
  float* dpart = (float*)alloc((size_t)BBATCH * 16 * 64 * 4);
  (void)meaninv;

  if (off > ws_size) return;   // diagnostic: ws too small -> clean absmax fail

  unsigned short* tm = bufA;   // live: tmix .. w1-GEMM
  unsigned short* xg = bufA;   // live: mix .. g-GEMM
  unsigned short* xr = bufB;   // live: mix .. r-GEMM
  unsigned short* kb = bufB;   // live: k-GEMM .. attn
  unsigned short* yb = bufB;   // live: ynorm .. out-GEMM
  unsigned short* xk = bufC;   // live: mix .. k-GEMM
  unsigned short* vb = bufC;   // live: v-GEMM .. attn
  unsigned short* xv = bufD;   // live: mix .. v-GEMM
  unsigned short* gb = bufD;   // live: g-GEMM .. ynorm
  unsigned short* rb = bufE;   // live: r-GEMM .. attn

  dim3 tb(32, 8);
  tcast5_kernel<<<dim3(64, 64, 5), tb, 0, stream>>>(recw, keyw, valw, gatew, outw,
                                                    wr_t, wk_t, wv_t, wg_t, wo_t);
  tcast_kernel<<<dim3(5, 64),  tb, 0, stream>>>(w1,    w1_t, 2048, 160);
  zero_stats_kernel<<<1, 128, 0, stream>>>(gsum, gsqs);

  tmix_kernel<<<16384, 256, 0, stream>>>(hidden, attn_x, tmaa_x, tm);

  gemm_kernel<1, 0><<<dim3(2, 64), 256, 0, stream>>>(tm, w1_t, xxx, MROWS, 160, HID, 160);

  mix_kernel<<<dim3(32, 128), 256, 0, stream>>>(xxx, hidden, attn_x, w2,
      tmaa_k, tmaa_v, tmaa_r, tmaa_g, xk, xv, xr, xg);

  // fused r/k/v/g projections: one dispatch, grid (8,32,4), z=3 silu
  gemm256x4_kernel<<<dim3(8, 32, 4), 512, 0, stream>>>(
      xr, xk, xv, xg, wr_t, wk_t, wv_t, wg_t, rb, kb, vb, gb, HID);

  // attn writes bf16 out0 over d_out[0,32MiB) (weight staging dead by now)
  attn_kernel<<<dim3(8, 128), 256, 0, stream>>>(rb, kb, vb, attn_kv, faaaa,
                                                out0b, gsum, gsqs);
  ynorm_kernel<<<16384, 256, 0, stream>>>(out0b, gb, gsum, gsqs, gamma, beta, yb);

  gemm256f_kernel<<<dim3(8, 32), 512, 0, stream>>>(yb, wo_t, out_main, HID);

  lastrow_mix_kernel<<<dim3(8, 4), 256, 0, stream>>>(xxx, hidden, w2, tmaa_w, tmaa_k, tmaa_v,
                                                     xw_l, xk_l, xv_l);
  decay1_part_kernel<<<dim3(16, 4), 256, 0, stream>>>(xw_l, tdw1, dpart);
  decay1_reduce_kernel<<<1, 256, 0, stream>>>(dpart, hdec);
  lastrow_kv_part_kernel<<<dim3(8, 16), 256, 0, stream>>>(xk_l, xv_l, keyw, valw, kpart, vpart);
  lastrow_kv_reduce_kernel<<<8, 256, 0, stream>>>(kpart, vpart, hdec, tdw2, tdecay,
                                                  klast, vlast, wlast);
  newkv_kernel<<<2048, 256, 0, stream>>>(klast, vlast, wlast, attn_kv, out_kv);
  copies_kernel<<<32, 256, 0, stream>>>(hidden, ffn_x, out_attnx, out_ffn);
}

// Round 11
// 642.386 us; speedup vs baseline: 1.1004x; 1.0539x over previous
//
#include <hip/hip_runtime.h>

#define HID 2048
#define TSEQ 2048
#define BBATCH 4
#define MROWS 8192   // B*T
#define NHEADS 32

typedef float fvec4 __attribute__((ext_vector_type(4)));
typedef unsigned short usvec4 __attribute__((ext_vector_type(4)));
typedef unsigned short usvec8 __attribute__((ext_vector_type(8)));
typedef __bf16 bh8 __attribute__((ext_vector_type(8)));
typedef float f32x4 __attribute__((ext_vector_type(4)));

__device__ __forceinline__ float bf2f(unsigned short u){
  return __uint_as_float(((unsigned int)u) << 16);
}
__device__ __forceinline__ unsigned short f2bf(float f){
  unsigned int u = __float_as_uint(f);
  return (unsigned short)((u + 0x7fffu + ((u >> 16) & 1u)) >> 16);
}
__device__ __forceinline__ void gll16(const void* g, void* lds){
  __builtin_amdgcn_global_load_lds(
      (const __attribute__((address_space(1))) unsigned int*)g,
      (__attribute__((address_space(3))) unsigned int*)lds, 16, 0, 0);
}

// pipeline sync: counted vmcnt + raw barrier in ONE asm (memory clobber blocks
// IR-level motion) + sched_barrier(0) (blocks MIR scheduler motion) — T4.
#define PIPE_SYNC(NSTR)                                              \
  asm volatile("s_waitcnt vmcnt(" NSTR ")\n\ts_barrier" ::: "memory"); \
  __builtin_amdgcn_sched_barrier(0);

// ---- 6 weight transposes f32->bf16 in ONE dispatch (z selects; z=5 is w1) --
__global__ void tcast6_kernel(const float* __restrict__ i0, const float* __restrict__ i1,
                              const float* __restrict__ i2, const float* __restrict__ i3,
                              const float* __restrict__ i4, const float* __restrict__ i5,
                              unsigned short* __restrict__ o0, unsigned short* __restrict__ o1,
                              unsigned short* __restrict__ o2, unsigned short* __restrict__ o3,
                              unsigned short* __restrict__ o4, unsigned short* __restrict__ o5){
  const float* in; unsigned short* out; int C = 2048;
  switch (blockIdx.z){
    case 0:  in = i0; out = o0; break;
    case 1:  in = i1; out = o1; break;
    case 2:  in = i2; out = o2; break;
    case 3:  in = i3; out = o3; break;
    case 4:  in = i4; out = o4; break;
    default: in = i5; out = o5; C = 160; break;
  }
  int c0 = blockIdx.x * 32, r0 = blockIdx.y * 32;
  if (c0 >= C) return;
  __shared__ float tile[32][33];
  int tx = threadIdx.x, ty = threadIdx.y;
  for (int i = ty; i < 32; i += 8){
    int c = c0 + tx;
    tile[i][tx] = (c < C) ? in[(size_t)(r0 + i) * C + c] : 0.f;
  }
  __syncthreads();
  for (int i = ty; i < 32; i += 8){
    int c = c0 + i;
    if (c < C) out[(size_t)c * 2048 + r0 + tx] = f2bf(tile[tx][i]);
  }
}

// ---------------- token-shift time_mix -> bf16 (+ stats zeroing) ------------
__global__ void tmix_kernel(const float* __restrict__ hidden, const float* __restrict__ attn_x,
                            const float* __restrict__ tmx, unsigned short* __restrict__ tm,
                            float* __restrict__ gsum, float* __restrict__ gsqs){
  if (blockIdx.x == 0 && threadIdx.x < 128){
    gsum[threadIdx.x] = 0.f;
    gsqs[threadIdx.x] = 0.f;
  }
  int i4 = blockIdx.x * 256 + threadIdx.x;        // over MROWS*HID/4
  int row = i4 >> 9;
  int c4 = i4 & 511;
  fvec4 x = *(const fvec4*)&hidden[(size_t)i4 * 4];
  fvec4 p;
  if ((row & (TSEQ - 1)) == 0){
    int b = row >> 11;
    p = *(const fvec4*)&attn_x[b * HID + c4 * 4];
  } else {
    p = *(const fvec4*)&hidden[(size_t)(i4 - 512) * 4];
  }
  fvec4 tx = *(const fvec4*)&tmx[c4 * 4];
  fvec4 t = x + (p - x) * tx;
  usvec4 o;
  o[0]=f2bf(t[0]); o[1]=f2bf(t[1]); o[2]=f2bf(t[2]); o[3]=f2bf(t[3]);
  *(usvec4*)&tm[(size_t)i4 * 4] = o;
}

// ---------------- m97-style bf16 GEMM (kept for the N=160 w1 GEMM) ----------
// ACT: 0 none, 1 tanh, 2 silu.  OUTBF16: store bf16 else f32.
template<int ACT, int OUTBF16>
__global__ __launch_bounds__(256, 2) void gemm_kernel(
    const unsigned short* __restrict__ A, const unsigned short* __restrict__ Bt,
    void* __restrict__ Cptr, int M, int N, int K, int ldc)
{
  __shared__ unsigned short As[128 * 32];
  __shared__ unsigned short Bs[128 * 32];
  const int tid = threadIdx.x;
  const int lane = tid & 63;
  const int w = tid >> 6;
  const int wr = w >> 1, wc = w & 1;
  const int lr = lane & 15, lq = lane >> 4;
  const int rowBase = blockIdx.y * 128;
  const int colBase = blockIdx.x * 128;

  const int arow = tid >> 2;
  const int ach = tid & 3;
  const unsigned short* aptr0 = A + (size_t)(rowBase + arow) * K + ach * 8;
  const unsigned short* aptr1 = aptr0 + (size_t)64 * K;
  int br0 = colBase + arow;      if (br0 > N - 1) br0 = N - 1;
  int br1 = colBase + arow + 64; if (br1 > N - 1) br1 = N - 1;
  const unsigned short* bptr0 = Bt + (size_t)br0 * K + ach * 8;
  const unsigned short* bptr1 = Bt + (size_t)br1 * K + ach * 8;

  f32x4 acc[4][4] = {};

  const int nk = K >> 5;
  for (int kk = 0; kk < nk; ++kk){
    gll16(aptr0, &As[tid * 8]);
    gll16(aptr1, &As[(tid + 256) * 8]);
    gll16(bptr0, &Bs[tid * 8]);
    gll16(bptr1, &Bs[(tid + 256) * 8]);
    aptr0 += 32; aptr1 += 32; bptr0 += 32; bptr1 += 32;
    __syncthreads();
    bh8 af[4], bfv[4];
    #pragma unroll
    for (int m = 0; m < 4; ++m)
      af[m] = *reinterpret_cast<const bh8*>(&As[(wr * 64 + m * 16 + lr) * 32 + lq * 8]);
    #pragma unroll
    for (int n = 0; n < 4; ++n)
      bfv[n] = *reinterpret_cast<const bh8*>(&Bs[(wc * 64 + n * 16 + lr) * 32 + lq * 8]);
    #pragma unroll
    for (int m = 0; m < 4; ++m)
      #pragma unroll
      for (int n = 0; n < 4; ++n)
        acc[m][n] = __builtin_amdgcn_mfma_f32_16x16x32_bf16(af[m], bfv[n], acc[m][n], 0, 0, 0);
    __syncthreads();
  }

  #pragma unroll
  for (int m = 0; m < 4; ++m){
    int gr0 = rowBase + wr * 64 + m * 16 + lq * 4;
    #pragma unroll
    for (int n = 0; n < 4; ++n){
      int gc = colBase + wc * 64 + n * 16 + lr;
      if (gc < N){
        #pragma unroll
        for (int q = 0; q < 4; ++q){
          float v = acc[m][n][q];
          if constexpr (ACT == 1) v = tanhf(v);
          else if constexpr (ACT == 2) v = v / (1.0f + __expf(-v));
          size_t off = (size_t)(gr0 + q) * ldc + gc;
          if constexpr (OUTBF16) ((unsigned short*)Cptr)[off] = f2bf(v);
          else                   ((float*)Cptr)[off] = v;
        }
      }
    }
  }
}

// -- 256x256 bf16 GEMM, BK=32, 4-buffer LDS, counted-vmcnt pipeline (T3+T4) --
// C = A(MxK) * Bt(NxK)^T.  M,N multiples of 256, K multiple of 32 (>=128).
// Swizzle: LDS[r][c] holds global chunk c ^ ((r>>1)&3); read-side per-lane
// constant ksel. XCD-aware block remap (T1). act runtime: 0 none, 2 silu.
template<int OUTBF16>
__device__ __forceinline__ void gemm256_body(
    const unsigned short* __restrict__ A, const unsigned short* __restrict__ Bt,
    void* __restrict__ Cptr, int K, int act)
{
  __shared__ unsigned short smem[65536];   // 4 buf x (A 8192 + B 8192) elems
  const int tid = threadIdx.x;
  const int lane = tid & 63, w = tid >> 6;
  const int wr = w >> 2, wc = w & 3;           // 2M x 4N waves
  const int lr = lane & 15, lq = lane >> 4;

  // T1: XCD-aware bijective remap (grid 8x32 = 256 blocks = 1/CU per slice)
  const int bid = blockIdx.y * gridDim.x + blockIdx.x;
  const int xcd = bid & 7, qq = bid >> 3;
  const int by = xcd * 4 + (qq >> 3);          // 0..31
  const int bx = qq & 7;                       // 0..7
  const int rowBase = by * 256;
  const int colBase = bx * 256;
  const int N = gridDim.x * 256;               // = ldc

  // staging descriptors: 2 gll A + 2 gll B per K-tile per thread
  const unsigned short* srcA[2]; const unsigned short* srcB[2];
  int dstA[2], dstB[2];
  #pragma unroll
  for (int l = 0; l < 2; ++l){
    int ci = l * 512 + tid;          // 0..1023
    int r = ci >> 2, c = ci & 3;     // row 0..255, chunk 0..3 (8 elems each)
    int g = c ^ ((r >> 1) & 3);      // pre-swizzled global chunk
    srcA[l] = A  + (size_t)(rowBase + r) * K + g * 8;
    srcB[l] = Bt + (size_t)(colBase + r) * K + g * 8;
    dstA[l] = ci * 8;
    dstB[l] = 8192 + ci * 8;
  }

  f32x4 acc[8][4] = {};
  const int ksel = (lq ^ ((lr >> 1) & 3)) * 8;   // per-lane swizzled k-chunk

  auto STAGE = [&](int t, int bi){
    unsigned short* buf = smem + bi * 16384;
    #pragma unroll
    for (int l = 0; l < 2; ++l){
      gll16(srcA[l] + (size_t)t * 32, buf + dstA[l]);
      gll16(srcB[l] + (size_t)t * 32, buf + dstB[l]);
    }
  };

  auto COMPUTE = [&](int bi){
    const unsigned short* aB = smem + bi * 16384;
    const unsigned short* bB = aB + 8192;
    bh8 af[8], bf[4];
    #pragma unroll
    for (int m = 0; m < 8; ++m)
      af[m] = *reinterpret_cast<const bh8*>(&aB[(wr * 128 + m * 16 + lr) * 32 + ksel]);
    #pragma unroll
    for (int n = 0; n < 4; ++n)
      bf[n] = *reinterpret_cast<const bh8*>(&bB[(wc * 64 + n * 16 + lr) * 32 + ksel]);
    __builtin_amdgcn_s_setprio(1);
    #pragma unroll
    for (int m = 0; m < 8; ++m)
      #pragma unroll
      for (int n = 0; n < 4; ++n)
        acc[m][n] = __builtin_amdgcn_mfma_f32_16x16x32_bf16(af[m], bf[n], acc[m][n], 0, 0, 0);
    __builtin_amdgcn_s_setprio(0);
  };

  const int nt = K >> 5;   // >= 4
  // prologue: prefetch tiles 0..2 (12 gll in flight; wait oldest 4 = tile 0)
  STAGE(0, 0); STAGE(1, 1); STAGE(2, 2);
  PIPE_SYNC("8");
  // steady state: stage t+3, compute t, wait tile t+1's loads (vmcnt 12->8)
  for (int t = 0; t < nt - 3; ++t){
    STAGE(t + 3, (t + 3) & 3);
    COMPUTE(t & 3);
    PIPE_SYNC("8");
  }
  COMPUTE((nt - 3) & 3);
  PIPE_SYNC("4");
  COMPUTE((nt - 2) & 3);
  PIPE_SYNC("0");
  COMPUTE((nt - 1) & 3);

  #pragma unroll
  for (int m = 0; m < 8; ++m){
    int gr0 = rowBase + wr * 128 + m * 16 + lq * 4;
    #pragma unroll
    for (int n = 0; n < 4; ++n){
      int gc = colBase + wc * 64 + n * 16 + lr;
      #pragma unroll
      for (int q = 0; q < 4; ++q){
        float v = acc[m][n][q];
        if (act == 2) v = v / (1.0f + __expf(-v));
        size_t off = (size_t)(gr0 + q) * N + gc;
        if constexpr (OUTBF16) ((unsigned short*)Cptr)[off] = f2bf(v);
        else                   ((float*)Cptr)[off] = v;
      }
    }
  }
}

// fused r/k/v/g projections: grid (8,32,4); z=3 applies silu
__global__ __launch_bounds__(512, 2) void gemm256x4_kernel(
    const unsigned short* __restrict__ A0, const unsigned short* __restrict__ A1,
    const unsigned short* __restrict__ A2, const unsigned short* __restrict__ A3,
    const unsigned short* __restrict__ B0, const unsigned short* __restrict__ B1,
    const unsigned short* __restrict__ B2, const unsigned short* __restrict__ B3,
    unsigned short* __restrict__ C0, unsigned short* __restrict__ C1,
    unsigned short* __restrict__ C2, unsigned short* __restrict__ C3, int K)
{
  const unsigned short* A; const unsigned short* Bt; unsigned short* C; int act = 0;
  switch (blockIdx.z){
    case 0:  A = A0; Bt = B0; C = C0; break;
    case 1:  A = A1; Bt = B1; C = C1; break;
    case 2:  A = A2; Bt = B2; C = C2; break;
    default: A = A3; Bt = B3; C = C3; act = 2; break;
  }
  gemm256_body<1>(A, Bt, C, K, act);
}

__global__ __launch_bounds__(512, 2) void gemm256f_kernel(
    const unsigned short* __restrict__ A, const unsigned short* __restrict__ Bt,
    float* __restrict__ C, int K)
{
  gemm256_body<0>(A, Bt, C, K, 0);
}

// ------- einsum(4x K=32) via MFMA + lerp construction of xk/xv/xr/xg --------
__global__ __launch_bounds__(256) void mix_kernel(
    const float* __restrict__ xxx, const float* __restrict__ hidden,
    const float* __restrict__ attn_x, const float* __restrict__ w2,
    const float* __restrict__ tmk, const float* __restrict__ tmv,
    const float* __restrict__ tmr, const float* __restrict__ tmg,
    unsigned short* __restrict__ xk, unsigned short* __restrict__ xv,
    unsigned short* __restrict__ xr, unsigned short* __restrict__ xg)
{
  __shared__ __attribute__((aligned(16))) unsigned short smem[20992];
  unsigned short* xs   = smem;           // [64][168] bf16
  unsigned short* w2t  = smem + 10752;   // [4][64][40] bf16 (w2t[n][cc][j])
  unsigned short* out4 = smem;           // [4][64][72] bf16 (phase B overlay)

  const int tid = threadIdx.x;
  const int r0 = blockIdx.y * 64, c0 = blockIdx.x * 64;
  const int w = tid >> 6, lane = tid & 63, lr = lane & 15, lq = lane >> 4;

  for (int idx = tid; idx < 64 * 40; idx += 256){
    int r = idx / 40, cq = idx - r * 40;
    fvec4 v = *(const fvec4*)&xxx[(size_t)(r0 + r) * 160 + cq * 4];
    usvec4 o;
    o[0]=f2bf(v[0]); o[1]=f2bf(v[1]); o[2]=f2bf(v[2]); o[3]=f2bf(v[3]);
    *(usvec4*)&xs[r * 168 + cq * 4] = o;
  }
  for (int idx = tid; idx < 4 * 32 * 16; idx += 256){
    int n = idx >> 9;
    int rem = idx & 511;
    int j = rem >> 4, cq = rem & 15;
    fvec4 v = *(const fvec4*)&w2[(size_t)((n + 1) * 32 + j) * HID + c0 + cq * 4];
    #pragma unroll
    for (int cc = 0; cc < 4; ++cc)
      w2t[(n * 64 + cq * 4 + cc) * 40 + j] = f2bf(v[cc]);
  }
  __syncthreads();

  f32x4 acc[4][4] = {};
  #pragma unroll
  for (int n = 0; n < 4; ++n){
    bh8 afr = *reinterpret_cast<const bh8*>(&xs[(w * 16 + lr) * 168 + (n + 1) * 32 + lq * 8]);
    #pragma unroll
    for (int ct = 0; ct < 4; ++ct){
      bh8 bfr = *reinterpret_cast<const bh8*>(&w2t[(n * 64 + ct * 16 + lr) * 40 + lq * 8]);
      acc[ct][n] = __builtin_amdgcn_mfma_f32_16x16x32_bf16(afr, bfr, acc[ct][n], 0, 0, 0);
    }
  }
  __syncthreads();

  #pragma unroll
  for (int ct = 0; ct < 4; ++ct){
    int gc = c0 + ct * 16 + lr;
    float tk_ = tmk[gc], tv_ = tmv[gc], tr_ = tmr[gc], tg_ = tmg[gc];
    #pragma unroll
    for (int q = 0; q < 4; ++q){
      int row64 = w * 16 + lq * 4 + q;
      int gr = r0 + row64;
      size_t rowoff = (size_t)gr * HID + gc;
      float xx = hidden[rowoff];
      float pp = ((gr & (TSEQ - 1)) == 0) ? attn_x[(gr >> 11) * HID + gc]
                                          : hidden[rowoff - HID];
      float dxv = pp - xx;
      int lo = row64 * 72 + ct * 16 + lr;
      out4[(0 * 64 * 72) + lo] = f2bf(xx + dxv * (tk_ + acc[ct][0][q]));
      out4[(1 * 64 * 72) + lo] = f2bf(xx + dxv * (tv_ + acc[ct][1][q]));
      out4[(2 * 64 * 72) + lo] = f2bf(xx + dxv * (tr_ + acc[ct][2][q]));
      out4[(3 * 64 * 72) + lo] = f2bf(xx + dxv * (tg_ + acc[ct][3][q]));
    }
  }
  __syncthreads();

  #pragma unroll
  for (int a = 0; a < 4; ++a){
    unsigned short* dst = (a == 0) ? xk : (a == 1) ? xv : (a == 2) ? xr : xg;
    #pragma unroll
    for (int pass = 0; pass < 2; ++pass){
      int row64 = pass * 32 + (tid >> 3);
      int c8 = (tid & 7) * 8;
      usvec8 v8 = *(const usvec8*)&out4[(a * 64 + row64) * 72 + c8];
      *(usvec8*)&dst[(size_t)(r0 + row64) * HID + c0 + c8] = v8;
    }
  }
}

// --------- attention via MFMA: out0 = r@akv + rk*v ; group stats ------------
__global__ __launch_bounds__(256) void attn_kernel(
    const unsigned short* __restrict__ rb, const unsigned short* __restrict__ kb,
    const unsigned short* __restrict__ vb, const float* __restrict__ attn_kv,
    const float* __restrict__ faaaa, unsigned short* __restrict__ out0b,
    float* __restrict__ gsum, float* __restrict__ gsqs)
{
  const int bh = blockIdx.y;           // 128 = b*32+h
  const int b = bh >> 5, h = bh & 31;
  const int tid = threadIdx.x, lane = tid & 63, w = tid >> 6;
  const int lr = lane & 15, lq = lane >> 4;
  const int t0 = blockIdx.x * 256 + w * 64;
  const size_t rowbase = (size_t)(b * TSEQ + t0) * HID + h * 64;

  const float* akvp = attn_kv + (size_t)bh * 4096;
  bh8 bfr[2][4];
  #pragma unroll
  for (int kk = 0; kk < 2; ++kk)
    #pragma unroll
    for (int n = 0; n < 4; ++n)
      #pragma unroll
      for (int j = 0; j < 8; ++j)
        bfr[kk][n][j] = (__bf16)akvp[(kk * 32 + lq * 8 + j) * 64 + n * 16 + lr];

  float fa0[8], fa1[8];
  #pragma unroll
  for (int j = 0; j < 8; ++j){
    fa0[j] = faaaa[h * 64 + lq * 8 + j];
    fa1[j] = faaaa[h * 64 + 32 + lq * 8 + j];
  }

  __shared__ __attribute__((aligned(16))) float rk_s[4][64];
  __shared__ __attribute__((aligned(16))) unsigned short outb[4][64][72];

  f32x4 acc[4][4] = {};
  #pragma unroll
  for (int m = 0; m < 4; ++m){
    size_t ra = rowbase + (size_t)(m * 16 + lr) * HID;
    bh8 a0 = *reinterpret_cast<const bh8*>(&rb[ra + lq * 8]);
    bh8 a1 = *reinterpret_cast<const bh8*>(&rb[ra + 32 + lq * 8]);
    usvec8 k0 = *reinterpret_cast<const usvec8*>(&kb[ra + lq * 8]);
    usvec8 k1 = *reinterpret_cast<const usvec8*>(&kb[ra + 32 + lq * 8]);
    float p = 0.f;
    #pragma unroll
    for (int j = 0; j < 8; ++j){
      p += (float)a0[j] * fa0[j] * bf2f(k0[j]);
      p += (float)a1[j] * fa1[j] * bf2f(k1[j]);
    }
    p += __shfl_xor(p, 16, 64);
    p += __shfl_xor(p, 32, 64);
    if (lq == 0) rk_s[w][m * 16 + lr] = p;
    #pragma unroll
    for (int n = 0; n < 4; ++n){
      acc[m][n] = __builtin_amdgcn_mfma_f32_16x16x32_bf16(a0, bfr[0][n], acc[m][n], 0, 0, 0);
      acc[m][n] = __builtin_amdgcn_mfma_f32_16x16x32_bf16(a1, bfr[1][n], acc[m][n], 0, 0, 0);
    }
  }
  __syncthreads();

  float ssum = 0.f, ssq = 0.f;
  #pragma unroll
  for (int m = 0; m < 4; ++m){
    fvec4 rk4 = *(const fvec4*)&rk_s[w][m * 16 + lq * 4];
    #pragma unroll
    for (int n = 0; n < 4; ++n){
      int col = n * 16 + lr;
      #pragma unroll
      for (int q = 0; q < 4; ++q){
        int row = m * 16 + lq * 4 + q;
        float vv = bf2f(vb[rowbase + (size_t)row * HID + col]);
        float o = acc[m][n][q] + rk4[q] * vv;
        ssum += o; ssq += o * o;
        outb[w][row][col] = f2bf(o);
      }
    }
  }
  __syncthreads();
  #pragma unroll
  for (int pass = 0; pass < 8; ++pass){
    int row = pass * 8 + (lane >> 3);
    int c8 = (lane & 7) * 8;
    usvec8 o8 = *(const usvec8*)&outb[w][row][c8];
    *(usvec8*)&out0b[rowbase + (size_t)row * HID + c8] = o8;
  }
  #pragma unroll
  for (int off2 = 32; off2 > 0; off2 >>= 1){
    ssum += __shfl_xor(ssum, off2, 64);
    ssq  += __shfl_xor(ssq,  off2, 64);
  }
  if (lane == 0){ atomicAdd(&gsum[bh], ssum); atomicAdd(&gsqs[bh], ssq); }
}

// ynorm with inlined group stats
__global__ void ynorm_kernel(const unsigned short* __restrict__ out0b,
                             const unsigned short* __restrict__ gb,
                             const float* __restrict__ gsum, const float* __restrict__ gsqs,
                             const float* __restrict__ gamma,
                             const float* __restrict__ beta, unsigned short* __restrict__ yb){
  int i4 = blockIdx.x * 256 + threadIdx.x;
  int row = i4 >> 9, c4 = i4 & 511;
  int b = row >> 11;
  int c = c4 * 4;
  int g = b * 32 + (c >> 6);
  const float rn = 1.0f / (float)(TSEQ * 64);
  float mean = gsum[g] * rn;
  float var  = gsqs[g] * rn - mean * mean;
  float inv  = rsqrtf(var + 1e-5f * 64.0f * 64.0f);
  usvec4 o4 = *(const usvec4*)&out0b[(size_t)i4 * 4];
  usvec4 gv = *(const usvec4*)&gb[(size_t)i4 * 4];
  fvec4 ga = *(const fvec4*)&gamma[c];
  fvec4 be = *(const fvec4*)&beta[c];
  usvec4 y;
  #pragma unroll
  for (int cc = 0; cc < 4; ++cc){
    float val = ((bf2f(o4[cc]) - mean) * inv * ga[cc] + be[cc]) * bf2f(gv[cc]);
    y[cc] = f2bf(val);
  }
  *(usvec4*)&yb[(size_t)i4 * 4] = y;
}

// ---------------- exact f32 last-row path (w / k_last / v_last) -------------
__global__ void lastrow_mix_kernel(const float* __restrict__ xxx, const float* __restrict__ hidden,
    const float* __restrict__ w2, const float* __restrict__ tmw, const float* __restrict__ tmk,
    const float* __restrict__ tmv, float* __restrict__ xw_l, float* __restrict__ xk_l,
    float* __restrict__ xv_l){
  int b = blockIdx.y;
  int c = blockIdx.x * 256 + threadIdx.x;
  __shared__ float xsr[160];
  int i = b * TSEQ + (TSEQ - 1);
  if (threadIdx.x < 160) xsr[threadIdx.x] = xxx[(size_t)i * 160 + threadIdx.x];
  __syncthreads();
  float mw = 0.f, mk = 0.f, mv = 0.f;
  for (int j = 0; j < 32; ++j){
    mw += xsr[j]      * w2[(size_t)(j)      * HID + c];
    mk += xsr[32 + j] * w2[(size_t)(32 + j) * HID + c];
    mv += xsr[64 + j] * w2[(size_t)(64 + j) * HID + c];
  }
  float x = hidden[(size_t)i * HID + c];
  float prev = hidden[(size_t)(i - 1) * HID + c];
  float dx = prev - x;
  xw_l[b * HID + c] = x + dx * (tmw[c] + mw);
  xk_l[b * HID + c] = x + dx * (tmk[c] + mk);
  xv_l[b * HID + c] = x + dx * (tmv[c] + mv);
}

// ---- decay part: dpart[b][chunk][j] = partial sums over 128 c-rows ---------
__global__ void decay1_part_kernel(const float* __restrict__ xw_l, const float* __restrict__ tdw1,
                                   float* __restrict__ dpart){
  int b = blockIdx.y;           // 4
  int chunk = blockIdx.x;       // 16 chunks of 128 c-rows
  int j = threadIdx.x & 63, sub = threadIdx.x >> 6;   // 4 subs x 32 rows
  float s = 0.f;
  int cbase = chunk * 128 + sub * 32;
  for (int r = 0; r < 32; ++r){
    int c = cbase + r;
    s += xw_l[b * HID + c] * tdw1[(size_t)c * 64 + j];
  }
  __shared__ float red[4][64];
  red[sub][j] = s;
  __syncthreads();
  if (sub == 0)
    dpart[((size_t)b * 16 + chunk) * 64 + j] = red[0][j] + red[1][j] + red[2][j] + red[3][j];
}

// ---- last-row k/v GEMVs: k-chunked partials (wide grid) + reduce -----------
__global__ __launch_bounds__(256) void lastrow_kv_part_kernel(
    const float* __restrict__ xk_l, const float* __restrict__ xv_l,
    const float* __restrict__ keyw, const float* __restrict__ valw,
    float* __restrict__ kpart, float* __restrict__ vpart){
  int c = blockIdx.x * 256 + threadIdx.x;   // 8 blocks -> 2048 cols
  int chunk = blockIdx.y;                   // 16 chunks of 128 rows
  __shared__ float xs[2][4][128];
  for (int i = threadIdx.x; i < 512; i += 256){
    int b = i >> 7, r = i & 127;
    xs[0][b][r] = xk_l[b * HID + chunk * 128 + r];
    xs[1][b][r] = xv_l[b * HID + chunk * 128 + r];
  }
  __syncthreads();
  float ka[4] = {0,0,0,0}, va[4] = {0,0,0,0};
  for (int r = 0; r < 128; ++r){
    int c2 = chunk * 128 + r;
    float kw = keyw[(size_t)c2 * HID + c];
    float vw = valw[(size_t)c2 * HID + c];
    #pragma unroll
    for (int b = 0; b < 4; ++b){
      ka[b] += xs[0][b][r] * kw;
      va[b] += xs[1][b][r] * vw;
    }
  }
  #pragma unroll
  for (int b = 0; b < 4; ++b){
    kpart[((size_t)chunk * 4 + b) * HID + c] = ka[b];
    vpart[((size_t)chunk * 4 + b) * HID + c] = va[b];
  }
}

// reduce + decay finish (hdec computed in-block from dpart) + w/exp
__global__ void lastrow_kv_reduce_kernel(
    const float* __restrict__ kpart, const float* __restrict__ vpart,
    const float* __restrict__ dpart, const float* __restrict__ tdw2,
    const float* __restrict__ tdecay, float* __restrict__ klast,
    float* __restrict__ vlast, float* __restrict__ wlast){
  __shared__ float hdec_s[256];
  {
    int t = threadIdx.x;            // 256 = 4 b x 64 j
    int b = t >> 6, j = t & 63;
    float s = 0.f;
    #pragma unroll
    for (int chunk = 0; chunk < 16; ++chunk)
      s += dpart[((size_t)b * 16 + chunk) * 64 + j];
    hdec_s[t] = tanhf(s);
  }
  __syncthreads();
  int c = blockIdx.x * 256 + threadIdx.x;   // 8 blocks -> 2048 cols
  float ka[4] = {0,0,0,0}, va[4] = {0,0,0,0};
  for (int chunk = 0; chunk < 16; ++chunk){
    #pragma unroll
    for (int b = 0; b < 4; ++b){
      ka[b] += kpart[((size_t)chunk * 4 + b) * HID + c];
      va[b] += vpart[((size_t)chunk * 4 + b) * HID + c];
    }
  }
  float tdc = tdecay[c];
  float td[4] = {tdc, tdc, tdc, tdc};
  for (int j = 0; j < 64; ++j){
    float w2v = tdw2[(size_t)j * HID + c];
    #pragma unroll
    for (int b = 0; b < 4; ++b) td[b] += hdec_s[b * 64 + j] * w2v;
  }
  #pragma unroll
  for (int b = 0; b < 4; ++b){
    klast[b * HID + c] = ka[b];
    vlast[b * HID + c] = va[b];
    wlast[b * HID + c] = expf(-expf(td[b]));
  }
}

// newkv + final copies in one dispatch (grid 2048 + 32 blocks)
__global__ void newkv_copies_kernel(const float* __restrict__ klast,
    const float* __restrict__ vlast, const float* __restrict__ wlast,
    const float* __restrict__ attn_kv, const float* __restrict__ hidden,
    const float* __restrict__ ffnx, float* __restrict__ outkv,
    float* __restrict__ out_attnx, float* __restrict__ out_ffnx){
  if (blockIdx.x < 2048){
    int idx = blockIdx.x * 256 + threadIdx.x;  // < 524288
    int b = idx >> 17;
    int h = (idx >> 12) & 31;
    int d = (idx >> 6) & 63;
    int e = idx & 63;
    float kl = klast[b * HID + h * 64 + d];
    float vl = vlast[b * HID + h * 64 + e];
    float wl = wlast[b * HID + h * 64 + d];
    outkv[idx] = kl * vl + wl * attn_kv[idx];
  } else {
    int i = (blockIdx.x - 2048) * 256 + threadIdx.x;  // < 8192
    int b = i >> 11, c = i & 2047;
    out_attnx[i] = hidden[((size_t)(b * TSEQ + TSEQ - 1)) * HID + c];
    out_ffnx[i] = ffnx[i];
  }
}

// ---------------------------------------------------------------------------
extern "C" void kernel_launch(void* const* d_in, const int* in_sizes, int n_in,
                              void* d_out, int out_size, void* d_ws, size_t ws_size,
                              hipStream_t stream)
{
  (void)in_sizes; (void)n_in; (void)out_size;
  const float* hidden = (const float*)d_in[0];
  const float* attn_x = (const float*)d_in[1];
  const float* attn_kv = (const float*)d_in[2];
  const float* ffn_x = (const float*)d_in[3];
  const float* tmaa_x = (const float*)d_in[4];
  const float* tmaa_w = (const float*)d_in[5];
  const float* tmaa_k = (const float*)d_in[6];
  const float* tmaa_v = (const float*)d_in[7];
  const float* tmaa_r = (const float*)d_in[8];
  const float* tmaa_g = (const float*)d_in[9];
  const float* w1 = (const float*)d_in[10];
  const float* w2 = (const float*)d_in[11];
  const float* tdecay = (const float*)d_in[12];
  const float* tdw1 = (const float*)d_in[13];
  const float* tdw2 = (const float*)d_in[14];
  const float* faaaa = (const float*)d_in[15];
  const float* recw = (const float*)d_in[16];
  const float* keyw = (const float*)d_in[17];
  const float* valw = (const float*)d_in[18];
  const float* gatew = (const float*)d_in[19];
  const float* outw = (const float*)d_in[20];
  const float* gamma = (const float*)d_in[21];
  const float* beta = (const float*)d_in[22];

  // output segments (all f32): out | new_attn_x | new_attn_kv | ffn_x
  float* out_main  = (float*)d_out;
  float* out_attnx = out_main + (size_t)16777216;
  float* out_kv    = out_attnx + 8192;
  float* out_ffn   = out_kv + 524288;

  // Early scratch inside d_out (finalized only by the last GEMM):
  //  phase 1 (GEMMs): 4 transposed bf16 weights in [0,32MiB)
  //  phase 2 (attn..ynorm): bf16 out0 in [0,32MiB)
  unsigned short* wr_t = (unsigned short*)d_out;              // 2048x2048 bf16
  unsigned short* wk_t = wr_t + (size_t)4194304;
  unsigned short* wv_t = wk_t + (size_t)4194304;
  unsigned short* wg_t = wv_t + (size_t)4194304;              // ends at 32 MiB
  unsigned short* out0b = (unsigned short*)d_out;             // MROWS*HID bf16

  // workspace layout (~175 MiB), liveness-aliased big buffers:
  //   A: tm -> xg   B: xr -> kb -> yb   C: xk -> vb   D: xv -> gb   E: rb
  char* ws = (char*)d_ws;
  size_t off = 0;
  auto alloc = [&](size_t bytes) -> void* {
    void* p = ws + off; off += (bytes + 255) & ~(size_t)255; return p;
  };
  unsigned short* wo_t = (unsigned short*)alloc(2048ull * 2048 * 2);
  unsigned short* w1_t = (unsigned short*)alloc(160ull * 2048 * 2);
  float* xxx           = (float*)alloc((size_t)MROWS * 160 * 4);
  unsigned short* bufA = (unsigned short*)alloc((size_t)MROWS * HID * 2);
  unsigned short* bufB = (unsigned short*)alloc((size_t)MROWS * HID * 2);
  unsigned short* bufC = (unsigned short*)alloc((size_t)MROWS * HID * 2);
  unsigned short* bufD = (unsigned short*)alloc((size_t)MROWS * HID * 2);
  unsigned short* bufE = (unsigned short*)alloc((size_t)MROWS * HID * 2);
  float* gsum    = (float*)alloc(128 * 4);
  float* gsqs    = (float*)alloc(128 * 4);
  float* xw_l  = (float*)alloc(BBATCH * HID * 4);
  float* xk_l  = (float*)alloc(BBATCH * HID * 4);
  float* xv_l  = (float*)alloc(BBATCH * HID * 4);
  float* klast = (float*)alloc(BBATCH * HID * 4);
  float* vlast = (float*)alloc(BBATCH * HID * 4);
  float* wlast = (float*)alloc(BBATCH * HID * 4);
  float* kpart = (float*)alloc(16ull * BBATCH * HID * 4);
  float* vpart = (float*)alloc(16ull * BBATCH * HID * 4);
  float* dpart = (float*)alloc((size_t)BBATCH * 16 * 64 * 4);

  if (off > ws_size) return;   // diagnostic: ws too small -> clean absmax fail

  unsigned short* tm = bufA;   // live: tmix .. w1-GEMM
  unsigned short* xg = bufA;   // live: mix .. g-GEMM
  unsigned short* xr = bufB;   // live: mix .. r-GEMM
  unsigned short* kb = bufB;   // live: k-GEMM .. attn
  unsigned short* yb = bufB;   // live: ynorm .. out-GEMM
  unsigned short* xk = bufC;   // live: mix .. k-GEMM
  unsigned short* vb = bufC;   // live: v-GEMM .. attn
  unsigned short* xv = bufD;   // live: mix .. v-GEMM
  unsigned short* gb = bufD;   // live: g-GEMM .. ynorm
  unsigned short* rb = bufE;   // live: r-GEMM .. attn

  dim3 tb(32, 8);
  tcast6_kernel<<<dim3(64, 64, 6), tb, 0, stream>>>(
      recw, keyw, valw, gatew, outw, w1,
      wr_t, wk_t, wv_t, wg_t, wo_t, w1_t);

  tmix_kernel<<<16384, 256, 0, stream>>>(hidden, attn_x, tmaa_x, tm, gsum, gsqs);

  gemm_kernel<1, 0><<<dim3(2, 64), 256, 0, stream>>>(tm, w1_t, xxx, MROWS, 160, HID, 160);

  mix_kernel<<<dim3(32, 128), 256, 0, stream>>>(xxx, hidden, attn_x, w2,
      tmaa_k, tmaa_v, tmaa_r, tmaa_g, xk, xv, xr, xg);

  // fused r/k/v/g projections: one dispatch, grid (8,32,4), z=3 silu
  gemm256x4_kernel<<<dim3(8, 32, 4), 512, 0, stream>>>(
      xr, xk, xv, xg, wr_t, wk_t, wv_t, wg_t, rb, kb, vb, gb, HID);

  // attn writes bf16 out0 over d_out[0,32MiB) (weight staging dead by now)
  attn_kernel<<<dim3(8, 128), 256, 0, stream>>>(rb, kb, vb, attn_kv, faaaa,
                                                out0b, gsum, gsqs);
  ynorm_kernel<<<16384, 256, 0, stream>>>(out0b, gb, gsum, gsqs, gamma, beta, yb);

  gemm256f_kernel<<<dim3(8, 32), 512, 0, stream>>>(yb, wo_t, out_main, HID);

  lastrow_mix_kernel<<<dim3(8, 4), 256, 0, stream>>>(xxx, hidden, w2, tmaa_w, tmaa_k, tmaa_v,
                                                     xw_l, xk_l, xv_l);
  decay1_part_kernel<<<dim3(16, 4), 256, 0, stream>>>(xw_l, tdw1, dpart);
  lastrow_kv_part_kernel<<<dim3(8, 16), 256, 0, stream>>>(xk_l, xv_l, keyw, valw, kpart, vpart);
  lastrow_kv_reduce_kernel<<<8, 256, 0, stream>>>(kpart, vpart, dpart, tdw2, tdecay,
                                                  klast, vlast, wlast);
  newkv_copies_kernel<<<2080, 256, 0, stream>>>(klast, vlast, wlast, attn_kv,
                                                hidden, ffn_x, out_kv,
                                                out_attnx, out_ffn);
}